// Round 5
// baseline (2999.746 us; speedup 1.0000x reference)
//
#include <hip/hip_runtime.h>
#include <math.h>

#define PI_HALF 1.57079632679489662f

__device__ __forceinline__ float fast_tanh(float x) {
    float e = __expf(2.f * x);
    return 1.f - 2.f * __builtin_amdgcn_rcpf(e + 1.f);
}

// ---------------- 4-qubit state helpers (compile-time masks -> registers) ----
// wire w (0..3) maps to amplitude-index bit (3-w), i.e. mask = 8 >> w.

__device__ __forceinline__ void prod_init(float sr[16],
        float c0, float s0, float c1, float s1,
        float c2, float s2, float c3, float s3) {
    float p2[4];
    p2[0] = c0 * c1; p2[1] = c0 * s1; p2[2] = s0 * c1; p2[3] = s0 * s1;
    float p3[8];
#pragma unroll
    for (int j = 0; j < 4; ++j) { p3[2 * j] = p2[j] * c2; p3[2 * j + 1] = p2[j] * s2; }
#pragma unroll
    for (int j = 0; j < 8; ++j) { sr[2 * j] = p3[j] * c3; sr[2 * j + 1] = p3[j] * s3; }
}

template<int M>
__device__ __forceinline__ void had_r(float sr[16]) {
    const float r = 0.70710678118654752f;
#pragma unroll
    for (int i = 0; i < 16; ++i) {
        if (i & M) continue;
        const int j = i | M;
        float ar = sr[i], br = sr[j];
        sr[i] = (ar + br) * r;
        sr[j] = (ar - br) * r;
    }
}

template<int MC, int MT>
__device__ __forceinline__ void cry_r(float sr[16], float c, float s) {
#pragma unroll
    for (int i = 0; i < 16; ++i) {
        if (!(i & MC) || (i & MT)) continue;
        const int j = i | MT;
        float ar = sr[i], br = sr[j];
        sr[i] = c * ar - s * br;
        sr[j] = s * ar + c * br;
    }
}

template<int MC, int MT>
__device__ __forceinline__ void cnot_r(float sr[16]) {
#pragma unroll
    for (int i = 0; i < 16; ++i) {
        if (!(i & MC) || (i & MT)) continue;
        const int j = i | MT;
        float t = sr[i]; sr[i] = sr[j]; sr[j] = t;
    }
}

template<int MC, int MT>
__device__ __forceinline__ void cnot_g(float sr[16], float si[16]) {
#pragma unroll
    for (int i = 0; i < 16; ++i) {
        if (!(i & MC) || (i & MT)) continue;
        const int j = i | MT;
        float tr = sr[i], ti = si[i];
        sr[i] = sr[j]; si[i] = si[j];
        sr[j] = tr;    si[j] = ti;
    }
}

template<int M>
__device__ __forceinline__ void rot_pre(float sr[16], float si[16], const float* __restrict__ u) {
    const float u00r = u[0], u00i = u[1], u01r = u[2], u01i = u[3];
    const float u10r = u[4], u10i = u[5], u11r = u[6], u11i = u[7];
#pragma unroll
    for (int i = 0; i < 16; ++i) {
        if (i & M) continue;
        const int j = i | M;
        float ar = sr[i], ai = si[i], br = sr[j], bi = si[j];
        sr[i] = u00r * ar - u00i * ai + u01r * br - u01i * bi;
        si[i] = u00r * ai + u00i * ar + u01r * bi + u01i * br;
        sr[j] = u10r * ar - u10i * ai + u11r * br - u11i * bi;
        si[j] = u10r * ai + u10i * ar + u11r * bi + u11i * br;
    }
}

// first Rot applied to a purely-real state (si implicitly 0); bitwise-identical
// to rot_pre with ai=bi=0 (dropped terms are exact zeros).
template<int M>
__device__ __forceinline__ void rot_first(float sr[16], float si[16], const float* __restrict__ u) {
    const float u00r = u[0], u00i = u[1], u01r = u[2], u01i = u[3];
    const float u10r = u[4], u10i = u[5], u11r = u[6], u11i = u[7];
#pragma unroll
    for (int i = 0; i < 16; ++i) {
        if (i & M) continue;
        const int j = i | M;
        float ar = sr[i], br = sr[j];
        sr[i] = u00r * ar + u01r * br;
        si[i] = u00i * ar + u01i * br;
        sr[j] = u10r * ar + u11r * br;
        si[j] = u10i * ar + u11i * br;
    }
}

__device__ __forceinline__ void zexp_g(const float sr[16], const float si[16], float z[4]) {
    float p[16];
#pragma unroll
    for (int i = 0; i < 16; ++i) p[i] = sr[i] * sr[i] + si[i] * si[i];
    z[0] = z[1] = z[2] = z[3] = 0.f;
#pragma unroll
    for (int i = 0; i < 16; ++i) {
        z[0] += (i & 8) ? -p[i] : p[i];
        z[1] += (i & 4) ? -p[i] : p[i];
        z[2] += (i & 2) ? -p[i] : p[i];
        z[3] += (i & 1) ? -p[i] : p[i];
    }
}

// ---------------- software grid barrier (all blocks co-resident) ------------
// Requires grid <= co-resident capacity (enforced by occupancy query at launch).
// syncthreads drains the block's stores; threadfence = agent-scope release
// (L2 writeback, cross-XCD visible); acquire load + fence on the wait side.
__device__ __forceinline__ void gsync(int* bar, int id) {
    __syncthreads();
    __threadfence();
    if (threadIdx.x == 0) {
        __hip_atomic_fetch_add(&bar[id], 1, __ATOMIC_ACQ_REL, __HIP_MEMORY_SCOPE_AGENT);
        while (__hip_atomic_load(&bar[id], __ATOMIC_ACQUIRE, __HIP_MEMORY_SCOPE_AGENT)
               < (int)gridDim.x)
            __builtin_amdgcn_s_sleep(2);
    }
    __syncthreads();
    __threadfence();
}

// ---------------- mega kernel: whole forward pass ---------------------------

struct MegaArgs {
    const float *x, *W_in, *b_in, *linW, *linb, *qpW, *qpb, *entp;
    const float *aqW, *aqb, *akW, *akb, *attqp, *pparm;
    const float *piW, *pib, *poW, *pob, *outW, *outb;
    const int *ei;
    float *h, *xcomb, *qbuf, *kbuf, *escore, *rotbuf, *Mm, *vv;
    int *cnt; float *sumexp; int *bar; int *off, *cur, *srcs, *inv;
    float *out;
    int N, E, EP;
};

__global__ void __launch_bounds__(256, 4) k_mega(MegaArgs a) {
    __shared__ float smem[4352];   // max alias: entlin 2 subs x (16*132 + 64)
    const int tid = threadIdx.x;
    const int bid = blockIdx.x;
    const int G = gridDim.x;
    const int gid = bid * 256 + tid;
    const int T = G * 256;
    const int N = a.N, E = a.E, EP = a.EP;

    // ======== P1: setup (block 0) + input GEMM (grid-stride tiles) + hist ====
    if (bid == 0) {
        const int t = tid;
        if (t < 36) {
            const float* p;
            if (t < 16)      p = a.entp  + t * 3;
            else if (t < 24) p = a.attqp + (t - 16) * 3;
            else             p = a.pparm + (t - 24) * 3;
            float phi = p[0], theta = p[1], omega = p[2];
            float st, ct; sincosf(0.5f * theta, &st, &ct);
            float sp, cp; sincosf(0.5f * (phi + omega), &sp, &cp);
            float sm, cm; sincosf(0.5f * (phi - omega), &sm, &cm);
            float* u = a.rotbuf + t * 8;
            u[0] =  ct * cp;  u[1] = -ct * sp;
            u[2] = -st * cm;  u[3] = -st * sm;
            u[4] =  st * cm;  u[5] = -st * sm;
            u[6] =  ct * cp;  u[7] =  ct * sp;
        } else if (t >= 64 && t < 192) {
            int t2 = t - 64;
            int o = t2 >> 2, i = t2 & 3;
            float acc = 0.f;
            for (int j = 0; j < 128; ++j) acc += a.outW[o * 128 + j] * a.poW[j * 4 + i];
            a.Mm[t2] = acc;
        } else if (t >= 192 && t < 224) {
            int o = t - 192;
            float acc = a.outb[o];
            for (int j = 0; j < 128; ++j) acc += a.outW[o * 128 + j] * a.pob[j];
            a.vv[o] = acc;
        }
    }
    {
        float* xs = smem;   // 32*64 floats
        const int ntile = (N + 31) >> 5;
        const int iters = (ntile + G - 1) / G;
        for (int it = 0; it < iters; ++it) {
            const int t = it * G + bid;
            const bool act = (t < ntile);
            const int base = t * 32;
            if (act) {
                for (int idx = tid; idx < 32 * 64; idx += 256) {
                    int n = base + (idx >> 6);
                    xs[idx] = (n < N) ? a.x[(size_t)n * 64 + (idx & 63)] : 0.f;
                }
            }
            __syncthreads();
            if (act) {
                const int ch = tid & 127;
                const int half = tid >> 7;
                float acc[16];
#pragma unroll
                for (int n = 0; n < 16; ++n) acc[n] = 0.f;
                const float4* wr4 = (const float4*)(a.W_in + ch * 64);
#pragma unroll 2
                for (int c4 = 0; c4 < 16; ++c4) {
                    float4 w = wr4[c4];
#pragma unroll
                    for (int n = 0; n < 16; ++n) {
                        float4 hv = *(const float4*)&xs[(half * 16 + n) * 64 + c4 * 4];
                        acc[n] += w.x * hv.x + w.y * hv.y + w.z * hv.z + w.w * hv.w;
                    }
                }
                const float bbv = a.b_in[ch];
#pragma unroll
                for (int n = 0; n < 16; ++n) {
                    int node = base + half * 16 + n;
                    if (node < N) a.h[(size_t)node * 128 + ch] = fmaxf(acc[n] + bbv, 0.f);
                }
            }
            __syncthreads();
        }
    }
    for (int e = gid; e < EP; e += T) {
        int d_ = (e < E) ? a.ei[E + e] : e - E;
        atomicAdd(&a.cnt[d_], 1);
    }
    gsync(a.bar, 0);

    // ======== P2: exclusive scan (block 0) ==================================
    if (bid == 0) {
        int* tot = (int*)smem;
        const int chunk = (N + 255) >> 8;
        const int s0 = tid * chunk;
        const int s1 = min(s0 + chunk, N);
        int sum = 0;
        for (int i = s0; i < s1; ++i) sum += a.cnt[i];
        tot[tid] = sum;
        __syncthreads();
        for (int d = 1; d < 256; d <<= 1) {
            int v = (tid >= d) ? tot[tid - d] : 0;
            __syncthreads();
            tot[tid] += v;
            __syncthreads();
        }
        int run = (tid == 0) ? 0 : tot[tid - 1];
        for (int i = s0; i < s1; ++i) {
            a.off[i] = run; a.cur[i] = run;
            run += a.cnt[i];
        }
    }
    gsync(a.bar, 1);

    // ======== P3: fill (counting-sort scatter) ==============================
    for (int e = gid; e < EP; e += T) {
        int s_, d_;
        if (e < E) { s_ = a.ei[e]; d_ = a.ei[E + e]; } else { s_ = d_ = e - E; }
        int pos = atomicAdd(&a.cur[d_], 1);
        a.srcs[pos] = s_;
        a.inv[e] = pos;
    }
    gsync(a.bar, 2);

    const int sub = tid >> 7;        // 128-thread sub-group id (0/1)
    const int tid128 = tid & 127;

    // ======== layer loop ====================================================
    for (int l = 0; l < 2; ++l) {
        const float* rotE2 = a.rotbuf + l * 64;
        const float* linWl = a.linW + (size_t)l * 128 * 128;
        const float* linbl = a.linb + l * 128;
        const float* qpWl  = a.qpW + (size_t)l * 512;
        const float* qpbl  = a.qpb + l * 128;
        const float* aqWl  = a.aqW + (size_t)l * 512;
        const float* aqbl  = a.aqb + l * 4;
        const float* akWl  = a.akW + (size_t)l * 512;
        const float* akbl  = a.akb + l * 4;

        // ---- P-ent: entangle circuit + linear/x_comb/q/k (16-node tiles) ----
        {
            float* hs  = smem + sub * 2176;   // 16*132
            float* xqs = hs + 2112;           // 16*4
            const int ntile = (N + 15) >> 4;
            const int slots = G * 2;
            const int iters = (ntile + slots - 1) / slots;
            for (int it = 0; it < iters; ++it) {
                const int t = it * slots + bid * 2 + sub;
                const bool act = (t < ntile);
                const int base = t * 16;
                if (act) {
                    for (int idx = tid128; idx < 16 * 32; idx += 128) {
                        int n = idx >> 5, c4 = idx & 31;
                        int node = base + n;
                        float4 hv = (node < N) ? *(const float4*)&a.h[(size_t)node * 128 + c4 * 4]
                                               : make_float4(0.f, 0.f, 0.f, 0.f);
                        *(float4*)&hs[n * 132 + c4 * 4] = hv;
                    }
                }
                __syncthreads();
                if (act) {
                    if (tid128 < 64) {
                        // wave 0 of sub: q/k dots (2 per lane)
#pragma unroll
                        for (int rep = 0; rep < 2; ++rep) {
                            const int dt = tid128 + rep * 64;
                            const int nl = dt >> 3;
                            const int which = dt & 7;
                            const int qi = which & 3;
                            const float4* Wp4 = (const float4*)(((which < 4) ? aqWl : akWl) + qi * 128);
                            float dot = (which < 4) ? aqbl[qi] : akbl[qi];
#pragma unroll 4
                            for (int c4 = 0; c4 < 32; ++c4) {
                                float4 w = Wp4[c4];
                                float4 hv = *(const float4*)&hs[nl * 132 + c4 * 4];
                                dot += w.x * hv.x + w.y * hv.y + w.z * hv.z + w.w * hv.w;
                            }
                            int node = base + nl;
                            if (node < N) {
                                float halfang = fast_tanh(dot) * (0.5f * PI_HALF);
                                float s, c; __sincosf(halfang, &s, &c);
                                float* dst = ((which < 4) ? a.qbuf : a.kbuf) + (size_t)node * 8 + qi * 2;
                                dst[0] = c; dst[1] = s;
                            }
                        }
                    } else if (tid128 < 80) {
                        // wave 1 lanes 0-15: entangle circuit (real until first Rot)
                        const int nl = tid128 - 64;
                        if (base + nl < N) {
                            float4 hv = *(const float4*)&hs[nl * 132];
                            float c0, s0, c1, s1, c2, s2, c3, s3;
                            { float aa = fast_tanh(hv.x) * (0.5f * PI_HALF); __sincosf(aa, &s0, &c0); }
                            { float aa = fast_tanh(hv.y) * (0.5f * PI_HALF); __sincosf(aa, &s1, &c1); }
                            { float aa = fast_tanh(hv.z) * (0.5f * PI_HALF); __sincosf(aa, &s2, &c2); }
                            { float aa = fast_tanh(hv.w) * (0.5f * PI_HALF); __sincosf(aa, &s3, &c3); }
                            float sr[16], si[16];
                            prod_init(sr, c0, s0, c1, s1, c2, s2, c3, s3);
                            cnot_r<8, 4>(sr); cnot_r<4, 2>(sr); cnot_r<2, 1>(sr);
                            rot_first<8>(sr, si, rotE2);
                            rot_pre<4>(sr, si, rotE2 + 8);
                            rot_pre<2>(sr, si, rotE2 + 16);
                            rot_pre<1>(sr, si, rotE2 + 24);
                            cnot_g<8, 1>(sr, si);
                            cnot_g<8, 4>(sr, si); cnot_g<4, 2>(sr, si); cnot_g<2, 1>(sr, si);
                            const float* P = rotE2 + 32;
                            rot_pre<8>(sr, si, P);
                            rot_pre<4>(sr, si, P + 8);
                            rot_pre<2>(sr, si, P + 16);
                            rot_pre<1>(sr, si, P + 24);
                            cnot_g<8, 1>(sr, si);
                            float z[4]; zexp_g(sr, si, z);
                            xqs[nl * 4 + 0] = z[0]; xqs[nl * 4 + 1] = z[1];
                            xqs[nl * 4 + 2] = z[2]; xqs[nl * 4 + 3] = z[3];
                        }
                    }
                }
                __syncthreads();
                if (act) {
                    // main GEMM: wave nh -> nodes nh*8..+7; lane -> ch, ch+64
                    const int lane = tid128 & 63;
                    const int nh = tid128 >> 6;
                    const int ch0 = lane, ch1 = lane + 64;
                    float acc0[8], acc1[8];
#pragma unroll
                    for (int n = 0; n < 8; ++n) { acc0[n] = 0.f; acc1[n] = 0.f; }
                    const float4* w04 = (const float4*)(linWl + ch0 * 128);
                    const float4* w14 = (const float4*)(linWl + ch1 * 128);
#pragma unroll 2
                    for (int c4 = 0; c4 < 32; ++c4) {
                        float4 wa = w04[c4];
                        float4 wb = w14[c4];
#pragma unroll
                        for (int n = 0; n < 8; ++n) {
                            float4 hv = *(const float4*)&hs[(nh * 8 + n) * 132 + c4 * 4];
                            acc0[n] += wa.x * hv.x + wa.y * hv.y + wa.z * hv.z + wa.w * hv.w;
                            acc1[n] += wb.x * hv.x + wb.y * hv.y + wb.z * hv.z + wb.w * hv.w;
                        }
                    }
                    const float b0 = linbl[ch0] + qpbl[ch0];
                    const float b1 = linbl[ch1] + qpbl[ch1];
                    const float q00 = qpWl[ch0 * 4 + 0], q01 = qpWl[ch0 * 4 + 1];
                    const float q02 = qpWl[ch0 * 4 + 2], q03 = qpWl[ch0 * 4 + 3];
                    const float q10 = qpWl[ch1 * 4 + 0], q11 = qpWl[ch1 * 4 + 1];
                    const float q12 = qpWl[ch1 * 4 + 2], q13 = qpWl[ch1 * 4 + 3];
#pragma unroll
                    for (int n = 0; n < 8; ++n) {
                        const int nl = nh * 8 + n;
                        const int node = base + nl;
                        if (node < N) {
                            float x0 = xqs[nl * 4 + 0], x1 = xqs[nl * 4 + 1];
                            float x2 = xqs[nl * 4 + 2], x3 = xqs[nl * 4 + 3];
                            a.xcomb[(size_t)node * 128 + ch0] = acc0[n] + b0
                                + q00 * x0 + q01 * x1 + q02 * x2 + q03 * x3;
                            a.xcomb[(size_t)node * 128 + ch1] = acc1[n] + b1
                                + q10 * x0 + q11 * x1 + q12 * x2 + q13 * x3;
                        }
                    }
                }
                __syncthreads();
            }
        }
        gsync(a.bar, 3 + l * 3);

        // ---- P-att: attention circuit per edge (grid-stride) ---------------
        {
            const float* RA = a.rotbuf + 128 + l * 32;
            float exsum = 0.f;
            for (int e = gid; e < EP; e += T) {
                int s_, d_;
                if (e < E) { s_ = a.ei[e]; d_ = a.ei[E + e]; } else { s_ = d_ = e - E; }
                float4 qa = *(const float4*)&a.qbuf[(size_t)s_ * 8];
                float4 qc = *(const float4*)&a.qbuf[(size_t)s_ * 8 + 4];
                float4 ka = *(const float4*)&a.kbuf[(size_t)d_ * 8];
                float4 kc = *(const float4*)&a.kbuf[(size_t)d_ * 8 + 4];
                float sr[16], si[16];
                prod_init(sr, qa.x, qa.y, qa.z, qa.w, qc.x, qc.y, qc.z, qc.w);
                had_r<8>(sr); had_r<4>(sr); had_r<2>(sr); had_r<1>(sr);
                cry_r<8, 4>(sr, ka.x, ka.y);
                cry_r<4, 2>(sr, ka.z, ka.w);
                cry_r<2, 1>(sr, kc.x, kc.y);
                cry_r<1, 8>(sr, kc.z, kc.w);
                rot_first<8>(sr, si, RA);
                rot_pre<4>(sr, si, RA + 8);
                rot_pre<2>(sr, si, RA + 16);
                rot_pre<1>(sr, si, RA + 24);
                float p0  = sr[0]  * sr[0]  + si[0]  * si[0];
                float p1  = sr[1]  * sr[1]  + si[1]  * si[1];
                float p2  = sr[2]  * sr[2]  + si[2]  * si[2];
                float p4  = sr[4]  * sr[4]  + si[4]  * si[4];
                float p8  = sr[8]  * sr[8]  + si[8]  * si[8];
                float p7  = sr[7]  * sr[7]  + si[7]  * si[7];
                float p11 = sr[11] * sr[11] + si[11] * si[11];
                float p13 = sr[13] * sr[13] + si[13] * si[13];
                float p14 = sr[14] * sr[14] + si[14] * si[14];
                float p15 = sr[15] * sr[15] + si[15] * si[15];
                float sc = (p0 - p15) + 0.5f * ((p1 + p2 + p4 + p8) - (p7 + p11 + p13 + p14));
                float ex = __expf(sc);
                a.escore[a.inv[e]] = ex;
                exsum += ex;
            }
#pragma unroll
            for (int d = 32; d; d >>= 1) exsum += __shfl_xor(exsum, d, 64);
            if ((tid & 63) == 0) atomicAdd(&a.sumexp[l], exsum);
        }
        gsync(a.bar, 4 + l * 3);

        // ---- P-gather: h[d,:] = relu(invS * sum escore*xcomb[src,:]) -------
        {
            const float invS = __builtin_amdgcn_rcpf(a.sumexp[l]);
            for (int d = bid * 2 + sub; d < N; d += G * 2) {
                const int start = a.off[d];
                const int num = a.cnt[d];
                float acc = 0.f;
                for (int i = 0; i < num; ++i)
                    acc += a.escore[start + i] * a.xcomb[(size_t)a.srcs[start + i] * 128 + tid128];
                a.h[(size_t)d * 128 + tid128] = fmaxf(acc * invS, 0.f);
            }
        }
        gsync(a.bar, 5 + l * 3);
    }

    // ======== P-tail: path_in proj + path circuit + fused epilogue ==========
    {
        float* pqS = smem;          // 64*8
        float* zS  = smem + 512;    // 64*4
        float* MS  = smem + 768;    // 128
        float* vS  = smem + 896;    // 32
        if (tid < 128) MS[tid] = a.Mm[tid];
        else if (tid < 160) vS[tid - 128] = a.vv[tid - 128];
        const float* RP = a.rotbuf + 192;
        const int ntile = (N + 63) >> 6;
        const int iters = (ntile + G - 1) / G;
        for (int it = 0; it < iters; ++it) {
            const int t = it * G + bid;
            const bool act = (t < ntile);
            const int base = t * 64;
            if (act) {
                const int nl = tid >> 2, i = tid & 3;
                const int node = base + nl;
                if (node < N) {
                    float dot = a.pib[i];
                    const float4* w4 = (const float4*)(a.piW + i * 128);
                    const float4* h4 = (const float4*)(a.h + (size_t)node * 128);
#pragma unroll 8
                    for (int c4 = 0; c4 < 32; ++c4) {
                        float4 w = w4[c4];
                        float4 hv = h4[c4];
                        dot += w.x * hv.x + w.y * hv.y + w.z * hv.z + w.w * hv.w;
                    }
                    float halfang = fast_tanh(dot) * (0.5f * PI_HALF);
                    float s, c; __sincosf(halfang, &s, &c);
                    pqS[nl * 8 + i * 2]     = c;
                    pqS[nl * 8 + i * 2 + 1] = s;
                }
            }
            __syncthreads();
            if (act && tid < 64 && base + tid < N) {
                const float r = 0.70710678118654752f;
                float c0 = pqS[tid * 8 + 0], s0 = pqS[tid * 8 + 1];
                float c1 = pqS[tid * 8 + 2], s1 = pqS[tid * 8 + 3];
                float c2 = pqS[tid * 8 + 4], s2 = pqS[tid * 8 + 5];
                float c3 = pqS[tid * 8 + 6], s3 = pqS[tid * 8 + 7];
                float u0 = r * (c0 - s0), w0 = r * (c0 + s0);
                float u1 = r * (c1 - s1), w1 = r * (c1 + s1);
                float u2 = r * (c2 - s2), w2 = r * (c2 + s2);
                float u3 = r * (c3 - s3), w3 = r * (c3 + s3);
                float sr[16], si[16];
                prod_init(sr, u0, w0, u1, w1, u2, w2, u3, w3);
                rot_first<8>(sr, si, RP);
                rot_pre<4>(sr, si, RP + 8);
                rot_pre<2>(sr, si, RP + 16);
                rot_pre<1>(sr, si, RP + 24);
                cnot_g<8, 4>(sr, si); cnot_g<4, 2>(sr, si); cnot_g<2, 1>(sr, si);
#pragma unroll
                for (int ll = 1; ll < 3; ++ll) {
                    const float* P = RP + ll * 32;
                    rot_pre<8>(sr, si, P);
                    rot_pre<4>(sr, si, P + 8);
                    rot_pre<2>(sr, si, P + 16);
                    rot_pre<1>(sr, si, P + 24);
                    cnot_g<8, 4>(sr, si); cnot_g<4, 2>(sr, si); cnot_g<2, 1>(sr, si);
                }
                float z[4]; zexp_g(sr, si, z);
                zS[tid * 4 + 0] = z[0]; zS[tid * 4 + 1] = z[1];
                zS[tid * 4 + 2] = z[2]; zS[tid * 4 + 3] = z[3];
            }
            __syncthreads();
            if (act) {
#pragma unroll
                for (int k = 0; k < 8; ++k) {
                    int flat = k * 256 + tid;
                    int nl = flat >> 5;
                    int o = flat & 31;
                    int node = base + nl;
                    if (node < N) {
                        a.out[(size_t)node * 32 + o] = vS[o]
                            + MS[o * 4 + 0] * zS[nl * 4 + 0] + MS[o * 4 + 1] * zS[nl * 4 + 1]
                            + MS[o * 4 + 2] * zS[nl * 4 + 2] + MS[o * 4 + 3] * zS[nl * 4 + 3];
                    }
                }
            }
            __syncthreads();
        }
    }
}

// ---------------- launch ----------------------------------------------------

extern "C" void kernel_launch(void* const* d_in, const int* in_sizes, int n_in,
                              void* d_out, int out_size, void* d_ws, size_t ws_size,
                              hipStream_t stream) {
    const int N  = in_sizes[0] / 64;   // 20000
    const int E  = in_sizes[20] / 2;   // 300000
    const int EP = E + N;              // self-loops appended

    float* ws     = (float*)d_ws;
    float* h      = ws;
    float* xcomb  = h      + (size_t)N * 128;
    float* qbuf   = xcomb  + (size_t)N * 128;
    float* kbuf   = qbuf   + (size_t)N * 8;
    float* escore = kbuf   + (size_t)N * 8;
    float* rotbuf = escore + EP;
    float* Mm     = rotbuf + 36 * 8;
    float* vv     = Mm + 128;
    int*   cnt    = (int*)(vv + 32);
    float* sumexp = (float*)(cnt + N);   // 4 slots, zeroed with cnt
    int*   bar    = (int*)(sumexp + 4);  // 16 barrier counters, zeroed with cnt
    int*   off    = bar + 16;
    int*   cur    = off + N;
    int*   srcs   = cur + N;
    int*   inv    = srcs + EP;

    MegaArgs ma;
    ma.x = (const float*)d_in[0];   ma.W_in = (const float*)d_in[1];
    ma.b_in = (const float*)d_in[2]; ma.linW = (const float*)d_in[3];
    ma.linb = (const float*)d_in[4]; ma.qpW = (const float*)d_in[5];
    ma.qpb = (const float*)d_in[6];  ma.entp = (const float*)d_in[7];
    ma.aqW = (const float*)d_in[8];  ma.aqb = (const float*)d_in[9];
    ma.akW = (const float*)d_in[10]; ma.akb = (const float*)d_in[11];
    ma.attqp = (const float*)d_in[12]; ma.pparm = (const float*)d_in[13];
    ma.piW = (const float*)d_in[14]; ma.pib = (const float*)d_in[15];
    ma.poW = (const float*)d_in[16]; ma.pob = (const float*)d_in[17];
    ma.outW = (const float*)d_in[18]; ma.outb = (const float*)d_in[19];
    ma.ei = (const int*)d_in[20];
    ma.h = h; ma.xcomb = xcomb; ma.qbuf = qbuf; ma.kbuf = kbuf;
    ma.escore = escore; ma.rotbuf = rotbuf; ma.Mm = Mm; ma.vv = vv;
    ma.cnt = cnt; ma.sumexp = sumexp; ma.bar = bar; ma.off = off; ma.cur = cur;
    ma.srcs = srcs; ma.inv = inv;
    ma.out = (float*)d_out;
    ma.N = N; ma.E = E; ma.EP = EP;

    // Grid sized to guaranteed co-residency (software grid barrier inside).
    static int G = 0;
    if (G == 0) {
        int maxb = 0;
        if (hipOccupancyMaxActiveBlocksPerMultiprocessor(&maxb, k_mega, 256, 0) != hipSuccess
            || maxb < 1) maxb = 1;
        int dev = 0;
        hipGetDevice(&dev);
        hipDeviceProp_t prop;
        int nCU = 256;
        if (hipGetDeviceProperties(&prop, dev) == hipSuccess && prop.multiProcessorCount > 0)
            nCU = prop.multiProcessorCount;
        long g = (long)maxb * nCU;
        if (g > 1024) g = 1024;
        if (g < 1) g = 1;
        G = (int)g;
    }

    // zero cnt[N] + sumexp[4] + bar[16]
    hipMemsetAsync(cnt, 0, (size_t)(N + 20) * sizeof(int), stream);
    hipLaunchKernelGGL(k_mega, dim3(G), dim3(256), 0, stream, ma);
}

// Round 6
// 801.450 us; speedup vs baseline: 3.7429x; 3.7429x over previous
//
#include <hip/hip_runtime.h>
#include <math.h>

#define PI_HALF 1.57079632679489662f

__device__ __forceinline__ float fast_tanh(float x) {
    float e = __expf(2.f * x);
    return 1.f - 2.f * __builtin_amdgcn_rcpf(e + 1.f);
}

// ---------------- 4-qubit state helpers (compile-time masks -> registers) ----
// wire w (0..3) maps to amplitude-index bit (3-w), i.e. mask = 8 >> w.

__device__ __forceinline__ void prod_init(float sr[16],
        float c0, float s0, float c1, float s1,
        float c2, float s2, float c3, float s3) {
    float p2[4];
    p2[0] = c0 * c1; p2[1] = c0 * s1; p2[2] = s0 * c1; p2[3] = s0 * s1;
    float p3[8];
#pragma unroll
    for (int j = 0; j < 4; ++j) { p3[2 * j] = p2[j] * c2; p3[2 * j + 1] = p2[j] * s2; }
#pragma unroll
    for (int j = 0; j < 8; ++j) { sr[2 * j] = p3[j] * c3; sr[2 * j + 1] = p3[j] * s3; }
}

template<int M>
__device__ __forceinline__ void had_r(float sr[16]) {
    const float r = 0.70710678118654752f;
#pragma unroll
    for (int i = 0; i < 16; ++i) {
        if (i & M) continue;
        const int j = i | M;
        float ar = sr[i], br = sr[j];
        sr[i] = (ar + br) * r;
        sr[j] = (ar - br) * r;
    }
}

template<int MC, int MT>
__device__ __forceinline__ void cry_r(float sr[16], float c, float s) {
#pragma unroll
    for (int i = 0; i < 16; ++i) {
        if (!(i & MC) || (i & MT)) continue;
        const int j = i | MT;
        float ar = sr[i], br = sr[j];
        sr[i] = c * ar - s * br;
        sr[j] = s * ar + c * br;
    }
}

template<int MC, int MT>
__device__ __forceinline__ void cnot_r(float sr[16]) {
#pragma unroll
    for (int i = 0; i < 16; ++i) {
        if (!(i & MC) || (i & MT)) continue;
        const int j = i | MT;
        float t = sr[i]; sr[i] = sr[j]; sr[j] = t;
    }
}

template<int MC, int MT>
__device__ __forceinline__ void cnot_g(float sr[16], float si[16]) {
#pragma unroll
    for (int i = 0; i < 16; ++i) {
        if (!(i & MC) || (i & MT)) continue;
        const int j = i | MT;
        float tr = sr[i], ti = si[i];
        sr[i] = sr[j]; si[i] = si[j];
        sr[j] = tr;    si[j] = ti;
    }
}

template<int M>
__device__ __forceinline__ void rot_pre(float sr[16], float si[16], const float* __restrict__ u) {
    const float u00r = u[0], u00i = u[1], u01r = u[2], u01i = u[3];
    const float u10r = u[4], u10i = u[5], u11r = u[6], u11i = u[7];
#pragma unroll
    for (int i = 0; i < 16; ++i) {
        if (i & M) continue;
        const int j = i | M;
        float ar = sr[i], ai = si[i], br = sr[j], bi = si[j];
        sr[i] = u00r * ar - u00i * ai + u01r * br - u01i * bi;
        si[i] = u00r * ai + u00i * ar + u01r * bi + u01i * br;
        sr[j] = u10r * ar - u10i * ai + u11r * br - u11i * bi;
        si[j] = u10r * ai + u10i * ar + u11r * bi + u11i * br;
    }
}

// first Rot applied to a purely-real state (si implicitly 0); bitwise-identical
// to rot_pre with ai=bi=0 (dropped terms are exact zeros).
template<int M>
__device__ __forceinline__ void rot_first(float sr[16], float si[16], const float* __restrict__ u) {
    const float u00r = u[0], u00i = u[1], u01r = u[2], u01i = u[3];
    const float u10r = u[4], u10i = u[5], u11r = u[6], u11i = u[7];
#pragma unroll
    for (int i = 0; i < 16; ++i) {
        if (i & M) continue;
        const int j = i | M;
        float ar = sr[i], br = sr[j];
        sr[i] = u00r * ar + u01r * br;
        si[i] = u00i * ar + u01i * br;
        sr[j] = u10r * ar + u11r * br;
        si[j] = u10i * ar + u11i * br;
    }
}

__device__ __forceinline__ void zexp_g(const float sr[16], const float si[16], float z[4]) {
    float p[16];
#pragma unroll
    for (int i = 0; i < 16; ++i) p[i] = sr[i] * sr[i] + si[i] * si[i];
    z[0] = z[1] = z[2] = z[3] = 0.f;
#pragma unroll
    for (int i = 0; i < 16; ++i) {
        z[0] += (i & 8) ? -p[i] : p[i];
        z[1] += (i & 4) ? -p[i] : p[i];
        z[2] += (i & 2) ? -p[i] : p[i];
        z[3] += (i & 1) ? -p[i] : p[i];
    }
}

// ---------------- kernels ---------------------------------------------------

// k_fsi: zero cnt/sumexp (completes at kernel boundary, before k_hist's atomics)
// + setup (block 0) + input GEMM h = relu(x @ W_in^T + b_in) (blocks 1..).
__global__ void k_fsi(const float* __restrict__ entp, const float* __restrict__ attqp,
                      const float* __restrict__ pparm,
                      const float* __restrict__ outW, const float* __restrict__ outb,
                      const float* __restrict__ poW, const float* __restrict__ pob,
                      float* __restrict__ rotbuf, float* __restrict__ M,
                      float* __restrict__ v,
                      const float* __restrict__ x, const float* __restrict__ W,
                      const float* __restrict__ b, float* __restrict__ h,
                      int* __restrict__ cnt, float* __restrict__ sumexp, int N) {
    __shared__ float xs[32 * 64];
    const int bb = blockIdx.x;
    const int tid = threadIdx.x;  // 256
    // zero role: grid-strided cnt + sumexp (hist runs in the NEXT kernel)
    {
        const int gid = bb * 256 + tid;
        const int T = gridDim.x * 256;
        for (int i = gid; i < N; i += T) cnt[i] = 0;
        if (gid < 4) sumexp[gid] = 0.f;
    }
    if (bb == 0) {
        // -------- setup role: rot matrices + fused output matrix --------
        const int t = tid;
        if (t < 36) {
            const float* p;
            if (t < 16)      p = entp  + t * 3;
            else if (t < 24) p = attqp + (t - 16) * 3;
            else             p = pparm + (t - 24) * 3;
            float phi = p[0], theta = p[1], omega = p[2];
            float st, ct; sincosf(0.5f * theta, &st, &ct);
            float sp, cp; sincosf(0.5f * (phi + omega), &sp, &cp);
            float sm, cm; sincosf(0.5f * (phi - omega), &sm, &cm);
            float* u = rotbuf + t * 8;
            u[0] =  ct * cp;  u[1] = -ct * sp;
            u[2] = -st * cm;  u[3] = -st * sm;
            u[4] =  st * cm;  u[5] = -st * sm;
            u[6] =  ct * cp;  u[7] =  ct * sp;
        } else if (t >= 64 && t < 192) {
            int t2 = t - 64;
            int o = t2 >> 2, i = t2 & 3;
            float acc = 0.f;
            for (int j = 0; j < 128; ++j) acc += outW[o * 128 + j] * poW[j * 4 + i];
            M[t2] = acc;
        } else if (t >= 192 && t < 224) {
            int o = t - 192;
            float acc = outb[o];
            for (int j = 0; j < 128; ++j) acc += outW[o * 128 + j] * pob[j];
            v[o] = acc;
        }
        return;
    }
    // -------- input-GEMM role: 32 nodes per block --------
    const int base = (bb - 1) * 32;
    for (int idx = tid; idx < 32 * 64; idx += 256) {
        int n = base + (idx >> 6);
        xs[idx] = (n < N) ? x[(size_t)n * 64 + (idx & 63)] : 0.f;
    }
    __syncthreads();
    const int ch = tid & 127;
    const int half = tid >> 7;
    float acc[16];
#pragma unroll
    for (int n = 0; n < 16; ++n) acc[n] = 0.f;
    const float4* wr4 = (const float4*)(W + ch * 64);
    for (int c4 = 0; c4 < 16; ++c4) {
        float4 w = wr4[c4];
#pragma unroll
        for (int n = 0; n < 16; ++n) {
            float4 hv = *(const float4*)&xs[(half * 16 + n) * 64 + c4 * 4];
            acc[n] += w.x * hv.x + w.y * hv.y + w.z * hv.z + w.w * hv.w;
        }
    }
    const float bbv = b[ch];
#pragma unroll
    for (int n = 0; n < 16; ++n) {
        int node = base + half * 16 + n;
        if (node < N) h[(size_t)node * 128 + ch] = fmaxf(acc[n] + bbv, 0.f);
    }
}

__global__ void k_hist(const int* __restrict__ ei, int* __restrict__ cnt, int E, int EP) {
    int e = blockIdx.x * blockDim.x + threadIdx.x;
    if (e >= EP) return;
    int d_ = (e < E) ? ei[E + e] : e - E;
    atomicAdd(&cnt[d_], 1);
}

__global__ void k_scan(const int* __restrict__ cnt, int* __restrict__ off,
                       int* __restrict__ cur, int N) {
    __shared__ int tot[1024];
    const int t = threadIdx.x;
    const int chunk = (N + 1023) >> 10;
    const int s0 = t * chunk;
    const int s1 = min(s0 + chunk, N);
    int sum = 0;
    for (int i = s0; i < s1; ++i) sum += cnt[i];
    tot[t] = sum;
    __syncthreads();
    for (int d = 1; d < 1024; d <<= 1) {
        int v = (t >= d) ? tot[t - d] : 0;
        __syncthreads();
        tot[t] += v;
        __syncthreads();
    }
    int run = (t == 0) ? 0 : tot[t - 1];
    for (int i = s0; i < s1; ++i) {
        off[i] = run; cur[i] = run;
        run += cnt[i];
    }
}

// entangle circuit + linear/x_comb/q/k. Blocks [0,eblf): fill role (counting-
// sort scatter; only on the layer-0 launch). sprev: previous layer's sumexp
// slot (nullptr for layer 0) — h is stored UN-normalized by k_attg, so the
// 1/S scale is applied here when staging (relu(x)/S == relu(x/S), S>0).
#define HS_STRIDE 132
__global__ void k_entlin(const float* __restrict__ h, const float* __restrict__ rotE2,
                         const float* __restrict__ linW, const float* __restrict__ linb,
                         const float* __restrict__ qpW, const float* __restrict__ qpb,
                         const float* __restrict__ aqW, const float* __restrict__ aqb,
                         const float* __restrict__ akW, const float* __restrict__ akb,
                         float* __restrict__ xcomb, float* __restrict__ qbuf,
                         float* __restrict__ kbuf, int N,
                         const float* __restrict__ sprev,
                         int eblf, const int* __restrict__ ei,
                         int* __restrict__ cur, int* __restrict__ srcs, int E, int EP) {
    __shared__ float hs[16 * HS_STRIDE];
    __shared__ float xqs[16 * 4];
    const int tid = threadIdx.x;  // 128
    if (blockIdx.x < eblf) {
        // -------- fill role --------
        int e = blockIdx.x * 128 + tid;
        if (e < EP) {
            int s_, d_;
            if (e < E) { s_ = ei[e]; d_ = ei[E + e]; } else { s_ = d_ = e - E; }
            int pos = atomicAdd(&cur[d_], 1);
            srcs[pos] = s_;
        }
        return;
    }
    const int base = (blockIdx.x - eblf) * 16;
    const float scale = sprev ? __builtin_amdgcn_rcpf(sprev[0]) : 1.0f;
    // stage h tile (float4, padded rows keep 16B alignment), scaled by 1/S
    for (int idx = tid; idx < 16 * 32; idx += 128) {
        int n = idx >> 5, c4 = idx & 31;
        int node = base + n;
        float4 hv = (node < N) ? *(const float4*)&h[(size_t)node * 128 + c4 * 4]
                               : make_float4(0.f, 0.f, 0.f, 0.f);
        hv.x *= scale; hv.y *= scale; hv.z *= scale; hv.w *= scale;
        *(float4*)&hs[n * HS_STRIDE + c4 * 4] = hv;
    }
    __syncthreads();
    if (tid < 64) {
        // wave 0: q/k dots. 128 dots = (node 0..15) x (which 0..7); 2 per lane.
#pragma unroll
        for (int rep = 0; rep < 2; ++rep) {
            const int dt = tid + rep * 64;
            const int nl = dt >> 3;
            const int which = dt & 7;
            const int qi = which & 3;
            const float4* Wp4 = (const float4*)(((which < 4) ? aqW : akW) + qi * 128);
            float dot = (which < 4) ? aqb[qi] : akb[qi];
            for (int c4 = 0; c4 < 32; ++c4) {
                float4 w = Wp4[c4];
                float4 hv = *(const float4*)&hs[nl * HS_STRIDE + c4 * 4];
                dot += w.x * hv.x + w.y * hv.y + w.z * hv.z + w.w * hv.w;
            }
            int node = base + nl;
            if (node < N) {
                float halfang = fast_tanh(dot) * (0.5f * PI_HALF);
                float s, c; __sincosf(halfang, &s, &c);
                float* dst = ((which < 4) ? qbuf : kbuf) + (size_t)node * 8 + qi * 2;
                dst[0] = c; dst[1] = s;
            }
        }
    } else if (tid < 80) {
        // wave 1 lanes 0-15: entangle circuit (real until first Rot).
        const int nl = tid - 64;
        if (base + nl < N) {
            float4 hv = *(const float4*)&hs[nl * HS_STRIDE];
            float c0, s0, c1, s1, c2, s2, c3, s3;
            { float a = fast_tanh(hv.x) * (0.5f * PI_HALF); __sincosf(a, &s0, &c0); }
            { float a = fast_tanh(hv.y) * (0.5f * PI_HALF); __sincosf(a, &s1, &c1); }
            { float a = fast_tanh(hv.z) * (0.5f * PI_HALF); __sincosf(a, &s2, &c2); }
            { float a = fast_tanh(hv.w) * (0.5f * PI_HALF); __sincosf(a, &s3, &c3); }
            float sr[16], si[16];
            prod_init(sr, c0, s0, c1, s1, c2, s2, c3, s3);
            cnot_r<8, 4>(sr); cnot_r<4, 2>(sr); cnot_r<2, 1>(sr);
            rot_first<8>(sr, si, rotE2);
            rot_pre<4>(sr, si, rotE2 + 8);
            rot_pre<2>(sr, si, rotE2 + 16);
            rot_pre<1>(sr, si, rotE2 + 24);
            cnot_g<8, 1>(sr, si);
            cnot_g<8, 4>(sr, si); cnot_g<4, 2>(sr, si); cnot_g<2, 1>(sr, si);
            const float* P = rotE2 + 32;
            rot_pre<8>(sr, si, P);
            rot_pre<4>(sr, si, P + 8);
            rot_pre<2>(sr, si, P + 16);
            rot_pre<1>(sr, si, P + 24);
            cnot_g<8, 1>(sr, si);
            float z[4]; zexp_g(sr, si, z);
            xqs[nl * 4 + 0] = z[0]; xqs[nl * 4 + 1] = z[1];
            xqs[nl * 4 + 2] = z[2]; xqs[nl * 4 + 3] = z[3];
        }
    }
    __syncthreads();
    // main GEMM: wave nh handles nodes nh*8..nh*8+7; lane handles ch=lane, lane+64.
    const int lane = tid & 63;
    const int nh = tid >> 6;
    const int ch0 = lane, ch1 = lane + 64;
    float acc0[8], acc1[8];
#pragma unroll
    for (int n = 0; n < 8; ++n) { acc0[n] = 0.f; acc1[n] = 0.f; }
    const float4* w04 = (const float4*)(linW + ch0 * 128);
    const float4* w14 = (const float4*)(linW + ch1 * 128);
    for (int c4 = 0; c4 < 32; ++c4) {
        float4 wa = w04[c4];
        float4 wb = w14[c4];
#pragma unroll
        for (int n = 0; n < 8; ++n) {
            float4 hv = *(const float4*)&hs[(nh * 8 + n) * HS_STRIDE + c4 * 4];
            acc0[n] += wa.x * hv.x + wa.y * hv.y + wa.z * hv.z + wa.w * hv.w;
            acc1[n] += wb.x * hv.x + wb.y * hv.y + wb.z * hv.z + wb.w * hv.w;
        }
    }
    const float b0 = linb[ch0] + qpb[ch0];
    const float b1 = linb[ch1] + qpb[ch1];
    const float q00 = qpW[ch0 * 4 + 0], q01 = qpW[ch0 * 4 + 1];
    const float q02 = qpW[ch0 * 4 + 2], q03 = qpW[ch0 * 4 + 3];
    const float q10 = qpW[ch1 * 4 + 0], q11 = qpW[ch1 * 4 + 1];
    const float q12 = qpW[ch1 * 4 + 2], q13 = qpW[ch1 * 4 + 3];
#pragma unroll
    for (int n = 0; n < 8; ++n) {
        const int nl = nh * 8 + n;
        const int node = base + nl;
        if (node < N) {
            float x0 = xqs[nl * 4 + 0], x1 = xqs[nl * 4 + 1];
            float x2 = xqs[nl * 4 + 2], x3 = xqs[nl * 4 + 3];
            xcomb[(size_t)node * 128 + ch0] = acc0[n] + b0
                + q00 * x0 + q01 * x1 + q02 * x2 + q03 * x3;
            xcomb[(size_t)node * 128 + ch1] = acc1[n] + b1
                + q10 * x0 + q11 * x1 + q12 * x2 + q13 * x3;
        }
    }
}

// fused attention + gather: one block per dst node. Computes this dst's edge
// circuits inline (kbuf[dst] read once), accumulates un-normalized weighted
// sum h_raw = relu(sum_e exp_e * xcomb[src_e]), and atomically adds the
// block's partial sum of exp to sumexp (the global softmax denominator is
// applied downstream: relu(x)/S == relu(x/S) for S>0).
__global__ void k_attg(const float* __restrict__ qb, const float* __restrict__ kb,
                       const float* __restrict__ RA, const int* __restrict__ srcs,
                       const int* __restrict__ off, const int* __restrict__ cnt,
                       const float* __restrict__ xcomb, float* __restrict__ sumexp,
                       float* __restrict__ h, int N) {
    __shared__ float wS[128];
    __shared__ int sS[128];
    __shared__ float red2[2];
    const int b = blockIdx.x;
    const int tid = threadIdx.x;  // 128
    const int start = off[b];
    const int num = cnt[b];
    const float4 ka = *(const float4*)&kb[(size_t)b * 8];
    const float4 kc = *(const float4*)&kb[(size_t)b * 8 + 4];
    float acc = 0.f;
    float exsum = 0.f;
    for (int base = 0; base < num; base += 128) {
        int m = min(128, num - base);
        if (tid < m) {
            int s_ = srcs[start + base + tid];
            sS[tid] = s_;
            float4 qa = *(const float4*)&qb[(size_t)s_ * 8];
            float4 qc = *(const float4*)&qb[(size_t)s_ * 8 + 4];
            float sr[16], si[16];
            prod_init(sr, qa.x, qa.y, qa.z, qa.w, qc.x, qc.y, qc.z, qc.w);
            had_r<8>(sr); had_r<4>(sr); had_r<2>(sr); had_r<1>(sr);
            cry_r<8, 4>(sr, ka.x, ka.y);
            cry_r<4, 2>(sr, ka.z, ka.w);
            cry_r<2, 1>(sr, kc.x, kc.y);
            cry_r<1, 8>(sr, kc.z, kc.w);
            rot_first<8>(sr, si, RA);
            rot_pre<4>(sr, si, RA + 8);
            rot_pre<2>(sr, si, RA + 16);
            rot_pre<1>(sr, si, RA + 24);
            float p0  = sr[0]  * sr[0]  + si[0]  * si[0];
            float p1  = sr[1]  * sr[1]  + si[1]  * si[1];
            float p2  = sr[2]  * sr[2]  + si[2]  * si[2];
            float p4  = sr[4]  * sr[4]  + si[4]  * si[4];
            float p8  = sr[8]  * sr[8]  + si[8]  * si[8];
            float p7  = sr[7]  * sr[7]  + si[7]  * si[7];
            float p11 = sr[11] * sr[11] + si[11] * si[11];
            float p13 = sr[13] * sr[13] + si[13] * si[13];
            float p14 = sr[14] * sr[14] + si[14] * si[14];
            float p15 = sr[15] * sr[15] + si[15] * si[15];
            float sc = (p0 - p15) + 0.5f * ((p1 + p2 + p4 + p8) - (p7 + p11 + p13 + p14));
            float ex = __expf(sc);
            wS[tid] = ex;
            exsum += ex;
        }
        __syncthreads();
        for (int i = 0; i < m; ++i)
            acc += wS[i] * xcomb[(size_t)sS[i] * 128 + tid];
        __syncthreads();
    }
    h[(size_t)b * 128 + tid] = fmaxf(acc, 0.f);
    // block-reduce exsum -> one atomicAdd
#pragma unroll
    for (int d = 32; d; d >>= 1) exsum += __shfl_xor(exsum, d, 64);
    if ((tid & 63) == 0) red2[tid >> 6] = exsum;
    __syncthreads();
    if (tid == 0) atomicAdd(sumexp, red2[0] + red2[1]);
}

// fused tail: path_in projection + path circuit + epilogue out = M@z + v.
// h is un-normalized (layer-1 attg output); the 1/S fold happens on the raw dot.
__global__ void k_tail(const float* __restrict__ h, const float* __restrict__ piW,
                       const float* __restrict__ pib, const float* __restrict__ RP,
                       const float* __restrict__ M, const float* __restrict__ v,
                       const float* __restrict__ sprev,
                       float* __restrict__ out, int N) {
    __shared__ float pqS[64 * 8];
    __shared__ float zS[64 * 4];
    __shared__ float MS[128];
    __shared__ float vS[32];
    const int tid = threadIdx.x;  // 256
    const int base = blockIdx.x * 64;
    if (tid < 128) MS[tid] = M[tid];
    else if (tid < 160) vS[tid - 128] = v[tid - 128];
    const float invS = __builtin_amdgcn_rcpf(sprev[0]);
    // phase 1: one projection dot per thread
    {
        const int nl = tid >> 2, i = tid & 3;
        const int node = base + nl;
        if (node < N) {
            float raw = 0.f;
            const float4* w4 = (const float4*)(piW + i * 128);
            const float4* h4 = (const float4*)(h + (size_t)node * 128);
#pragma unroll 8
            for (int c4 = 0; c4 < 32; ++c4) {
                float4 w = w4[c4];
                float4 hv = h4[c4];
                raw += w.x * hv.x + w.y * hv.y + w.z * hv.z + w.w * hv.w;
            }
            float dot = pib[i] + invS * raw;
            float halfang = fast_tanh(dot) * (0.5f * PI_HALF);
            float s, c; __sincosf(halfang, &s, &c);
            pqS[nl * 8 + i * 2]     = c;
            pqS[nl * 8 + i * 2 + 1] = s;
        }
    }
    __syncthreads();
    // phase 2: path circuit, one node per lane (lanes 0-63).
    if (tid < 64 && base + tid < N) {
        const float r = 0.70710678118654752f;
        float c0 = pqS[tid * 8 + 0], s0 = pqS[tid * 8 + 1];
        float c1 = pqS[tid * 8 + 2], s1 = pqS[tid * 8 + 3];
        float c2 = pqS[tid * 8 + 4], s2 = pqS[tid * 8 + 5];
        float c3 = pqS[tid * 8 + 6], s3 = pqS[tid * 8 + 7];
        float u0 = r * (c0 - s0), w0 = r * (c0 + s0);
        float u1 = r * (c1 - s1), w1 = r * (c1 + s1);
        float u2 = r * (c2 - s2), w2 = r * (c2 + s2);
        float u3 = r * (c3 - s3), w3 = r * (c3 + s3);
        float sr[16], si[16];
        prod_init(sr, u0, w0, u1, w1, u2, w2, u3, w3);
        rot_first<8>(sr, si, RP);
        rot_pre<4>(sr, si, RP + 8);
        rot_pre<2>(sr, si, RP + 16);
        rot_pre<1>(sr, si, RP + 24);
        cnot_g<8, 4>(sr, si); cnot_g<4, 2>(sr, si); cnot_g<2, 1>(sr, si);
#pragma unroll
        for (int l = 1; l < 3; ++l) {
            const float* P = RP + l * 32;
            rot_pre<8>(sr, si, P);
            rot_pre<4>(sr, si, P + 8);
            rot_pre<2>(sr, si, P + 16);
            rot_pre<1>(sr, si, P + 24);
            cnot_g<8, 4>(sr, si); cnot_g<4, 2>(sr, si); cnot_g<2, 1>(sr, si);
        }
        float z[4]; zexp_g(sr, si, z);
        zS[tid * 4 + 0] = z[0]; zS[tid * 4 + 1] = z[1];
        zS[tid * 4 + 2] = z[2]; zS[tid * 4 + 3] = z[3];
    }
    __syncthreads();
    // phase 3: epilogue, 64 nodes x 32 outputs, coalesced
#pragma unroll
    for (int k = 0; k < 8; ++k) {
        int flat = k * 256 + tid;
        int nl = flat >> 5;
        int o = flat & 31;
        int node = base + nl;
        if (node < N) {
            out[(size_t)node * 32 + o] = vS[o]
                + MS[o * 4 + 0] * zS[nl * 4 + 0] + MS[o * 4 + 1] * zS[nl * 4 + 1]
                + MS[o * 4 + 2] * zS[nl * 4 + 2] + MS[o * 4 + 3] * zS[nl * 4 + 3];
        }
    }
}

// ---------------- launch ----------------------------------------------------

extern "C" void kernel_launch(void* const* d_in, const int* in_sizes, int n_in,
                              void* d_out, int out_size, void* d_ws, size_t ws_size,
                              hipStream_t stream) {
    const float* x     = (const float*)d_in[0];
    const float* W_in  = (const float*)d_in[1];
    const float* b_in  = (const float*)d_in[2];
    const float* linW  = (const float*)d_in[3];
    const float* linb  = (const float*)d_in[4];
    const float* qpW   = (const float*)d_in[5];
    const float* qpb   = (const float*)d_in[6];
    const float* entp  = (const float*)d_in[7];
    const float* aqW   = (const float*)d_in[8];
    const float* aqb   = (const float*)d_in[9];
    const float* akW   = (const float*)d_in[10];
    const float* akb   = (const float*)d_in[11];
    const float* attqp = (const float*)d_in[12];
    const float* pparm = (const float*)d_in[13];
    const float* piW   = (const float*)d_in[14];
    const float* pib   = (const float*)d_in[15];
    const float* poW   = (const float*)d_in[16];
    const float* pob   = (const float*)d_in[17];
    const float* outW  = (const float*)d_in[18];
    const float* outb  = (const float*)d_in[19];
    const int*   ei    = (const int*)d_in[20];

    const int N  = in_sizes[0] / 64;   // 20000
    const int E  = in_sizes[20] / 2;   // 300000
    const int EP = E + N;              // self-loops appended

    float* ws     = (float*)d_ws;
    float* h      = ws;
    float* xcomb  = h      + (size_t)N * 128;
    float* qbuf   = xcomb  + (size_t)N * 128;
    float* kbuf   = qbuf   + (size_t)N * 8;
    float* rotbuf = kbuf   + (size_t)N * 8;
    float* Mm     = rotbuf + 36 * 8;
    float* vv     = Mm + 128;
    int*   cnt    = (int*)(vv + 32);
    float* sumexp = (float*)(cnt + N);   // 4 slots
    int*   off    = (int*)(sumexp + 4);
    int*   cur    = off + N;
    int*   srcs   = cur + N;

    const float* rotE = rotbuf;          // 16 matrices
    const float* rotA = rotbuf + 128;    // 8 matrices
    const float* rotP = rotbuf + 192;    // 12 matrices

    const int nb16 = (N + 15) / 16;
    const int nb32 = (N + 31) / 32;
    const int ebl  = (EP + 255) / 256;
    const int eblf = (EP + 127) / 128;

    // 1: zero(cnt,sumexp) + setup + input GEMM
    k_fsi<<<nb32 + 1, 256, 0, stream>>>(entp, attqp, pparm, outW, outb, poW, pob,
                                        rotbuf, Mm, vv, x, W_in, b_in, h,
                                        cnt, sumexp, N);
    // 2: histogram of dsts
    k_hist<<<ebl, 256, 0, stream>>>(ei, cnt, E, EP);
    // 3: exclusive scan
    k_scan<<<1, 1024, 0, stream>>>(cnt, off, cur, N);

    for (int l = 0; l < 2; ++l) {
        const int fillb = (l == 0) ? eblf : 0;
        // 4/6: fill (layer 0 only) + entangle + linear + q/k
        k_entlin<<<fillb + nb16, 128, 0, stream>>>(h, rotE + l * 64,
            linW + (size_t)l * 128 * 128, linb + l * 128,
            qpW + (size_t)l * 128 * 4, qpb + l * 128,
            aqW + (size_t)l * 4 * 128, aqb + l * 4,
            akW + (size_t)l * 4 * 128, akb + l * 4,
            xcomb, qbuf, kbuf, N,
            (l == 0) ? (const float*)nullptr : (const float*)(sumexp + 0),
            fillb, ei, cur, srcs, E, EP);
        // 5/7: fused attention-circuit + gather (un-normalized; partial sum of exp)
        k_attg<<<N, 128, 0, stream>>>(qbuf, kbuf, rotA + l * 32, srcs, off, cnt,
                                      xcomb, sumexp + l, h, N);
    }

    // 8: tail with 1/S fold
    k_tail<<<(N + 63) / 64, 256, 0, stream>>>(h, piW, pib, rotP, Mm, vv,
                                              sumexp + 1, (float*)d_out, N);
}

// Round 7
// 415.764 us; speedup vs baseline: 7.2150x; 1.9277x over previous
//
#include <hip/hip_runtime.h>
#include <math.h>

#define PI_HALF 1.57079632679489662f

__device__ __forceinline__ float fast_tanh(float x) {
    float e = __expf(2.f * x);
    return 1.f - 2.f * __builtin_amdgcn_rcpf(e + 1.f);
}

// ---------------- 4-qubit state helpers (compile-time masks -> registers) ----
// wire w (0..3) maps to amplitude-index bit (3-w), i.e. mask = 8 >> w.

__device__ __forceinline__ void prod_init(float sr[16],
        float c0, float s0, float c1, float s1,
        float c2, float s2, float c3, float s3) {
    float p2[4];
    p2[0] = c0 * c1; p2[1] = c0 * s1; p2[2] = s0 * c1; p2[3] = s0 * s1;
    float p3[8];
#pragma unroll
    for (int j = 0; j < 4; ++j) { p3[2 * j] = p2[j] * c2; p3[2 * j + 1] = p2[j] * s2; }
#pragma unroll
    for (int j = 0; j < 8; ++j) { sr[2 * j] = p3[j] * c3; sr[2 * j + 1] = p3[j] * s3; }
}

template<int M>
__device__ __forceinline__ void had_r(float sr[16]) {
    const float r = 0.70710678118654752f;
#pragma unroll
    for (int i = 0; i < 16; ++i) {
        if (i & M) continue;
        const int j = i | M;
        float ar = sr[i], br = sr[j];
        sr[i] = (ar + br) * r;
        sr[j] = (ar - br) * r;
    }
}

template<int MC, int MT>
__device__ __forceinline__ void cry_r(float sr[16], float c, float s) {
#pragma unroll
    for (int i = 0; i < 16; ++i) {
        if (!(i & MC) || (i & MT)) continue;
        const int j = i | MT;
        float ar = sr[i], br = sr[j];
        sr[i] = c * ar - s * br;
        sr[j] = s * ar + c * br;
    }
}

template<int MC, int MT>
__device__ __forceinline__ void cnot_r(float sr[16]) {
#pragma unroll
    for (int i = 0; i < 16; ++i) {
        if (!(i & MC) || (i & MT)) continue;
        const int j = i | MT;
        float t = sr[i]; sr[i] = sr[j]; sr[j] = t;
    }
}

template<int MC, int MT>
__device__ __forceinline__ void cnot_g(float sr[16], float si[16]) {
#pragma unroll
    for (int i = 0; i < 16; ++i) {
        if (!(i & MC) || (i & MT)) continue;
        const int j = i | MT;
        float tr = sr[i], ti = si[i];
        sr[i] = sr[j]; si[i] = si[j];
        sr[j] = tr;    si[j] = ti;
    }
}

template<int M>
__device__ __forceinline__ void rot_pre(float sr[16], float si[16], const float* __restrict__ u) {
    const float u00r = u[0], u00i = u[1], u01r = u[2], u01i = u[3];
    const float u10r = u[4], u10i = u[5], u11r = u[6], u11i = u[7];
#pragma unroll
    for (int i = 0; i < 16; ++i) {
        if (i & M) continue;
        const int j = i | M;
        float ar = sr[i], ai = si[i], br = sr[j], bi = si[j];
        sr[i] = u00r * ar - u00i * ai + u01r * br - u01i * bi;
        si[i] = u00r * ai + u00i * ar + u01r * bi + u01i * br;
        sr[j] = u10r * ar - u10i * ai + u11r * br - u11i * bi;
        si[j] = u10r * ai + u10i * ar + u11r * bi + u11i * br;
    }
}

// first Rot applied to a purely-real state (si implicitly 0); bitwise-identical
// to rot_pre with ai=bi=0 (dropped terms are exact zeros).
template<int M>
__device__ __forceinline__ void rot_first(float sr[16], float si[16], const float* __restrict__ u) {
    const float u00r = u[0], u00i = u[1], u01r = u[2], u01i = u[3];
    const float u10r = u[4], u10i = u[5], u11r = u[6], u11i = u[7];
#pragma unroll
    for (int i = 0; i < 16; ++i) {
        if (i & M) continue;
        const int j = i | M;
        float ar = sr[i], br = sr[j];
        sr[i] = u00r * ar + u01r * br;
        si[i] = u00i * ar + u01i * br;
        sr[j] = u10r * ar + u11r * br;
        si[j] = u10i * ar + u11i * br;
    }
}

__device__ __forceinline__ void zexp_g(const float sr[16], const float si[16], float z[4]) {
    float p[16];
#pragma unroll
    for (int i = 0; i < 16; ++i) p[i] = sr[i] * sr[i] + si[i] * si[i];
    z[0] = z[1] = z[2] = z[3] = 0.f;
#pragma unroll
    for (int i = 0; i < 16; ++i) {
        z[0] += (i & 8) ? -p[i] : p[i];
        z[1] += (i & 4) ? -p[i] : p[i];
        z[2] += (i & 2) ? -p[i] : p[i];
        z[3] += (i & 1) ? -p[i] : p[i];
    }
}

// ---------------- kernels ---------------------------------------------------

// k_fsi: zero cnt/sumexp (completes at kernel boundary, before k_hist's atomics)
// + setup (block 0) + input GEMM h = relu(x @ W_in^T + b_in) (blocks 1..).
// GEMM blocking: wave w owns nodes w*8..w*8+7; lane owns ch=lane, lane+64 so
// each xs b128 broadcast feeds 2 channel-accumulators (halves LDS issues).
__global__ void k_fsi(const float* __restrict__ entp, const float* __restrict__ attqp,
                      const float* __restrict__ pparm,
                      const float* __restrict__ outW, const float* __restrict__ outb,
                      const float* __restrict__ poW, const float* __restrict__ pob,
                      float* __restrict__ rotbuf, float* __restrict__ M,
                      float* __restrict__ v,
                      const float* __restrict__ x, const float* __restrict__ W,
                      const float* __restrict__ b, float* __restrict__ h,
                      int* __restrict__ cnt, float* __restrict__ sumexp, int N) {
    __shared__ float xs[32 * 64];
    const int bb = blockIdx.x;
    const int tid = threadIdx.x;  // 256
    // zero role: grid-strided cnt + sumexp (hist runs in the NEXT kernel)
    {
        const int gid = bb * 256 + tid;
        const int T = gridDim.x * 256;
        for (int i = gid; i < N; i += T) cnt[i] = 0;
        if (gid < 4) sumexp[gid] = 0.f;
    }
    if (bb == 0) {
        // -------- setup role: rot matrices + fused output matrix --------
        const int t = tid;
        if (t < 36) {
            const float* p;
            if (t < 16)      p = entp  + t * 3;
            else if (t < 24) p = attqp + (t - 16) * 3;
            else             p = pparm + (t - 24) * 3;
            float phi = p[0], theta = p[1], omega = p[2];
            float st, ct; sincosf(0.5f * theta, &st, &ct);
            float sp, cp; sincosf(0.5f * (phi + omega), &sp, &cp);
            float sm, cm; sincosf(0.5f * (phi - omega), &sm, &cm);
            float* u = rotbuf + t * 8;
            u[0] =  ct * cp;  u[1] = -ct * sp;
            u[2] = -st * cm;  u[3] = -st * sm;
            u[4] =  st * cm;  u[5] = -st * sm;
            u[6] =  ct * cp;  u[7] =  ct * sp;
        } else if (t >= 64 && t < 192) {
            int t2 = t - 64;
            int o = t2 >> 2, i = t2 & 3;
            float acc = 0.f;
            for (int j = 0; j < 128; ++j) acc += outW[o * 128 + j] * poW[j * 4 + i];
            M[t2] = acc;
        } else if (t >= 192 && t < 224) {
            int o = t - 192;
            float acc = outb[o];
            for (int j = 0; j < 128; ++j) acc += outW[o * 128 + j] * pob[j];
            v[o] = acc;
        }
        return;
    }
    // -------- input-GEMM role: 32 nodes per block --------
    const int base = (bb - 1) * 32;
    for (int idx = tid; idx < 32 * 64; idx += 256) {
        int n = base + (idx >> 6);
        xs[idx] = (n < N) ? x[(size_t)n * 64 + (idx & 63)] : 0.f;
    }
    __syncthreads();
    const int lane = tid & 63;
    const int wv = tid >> 6;            // wave 0..3 -> nodes wv*8..wv*8+7
    const int ch0 = lane, ch1 = lane + 64;
    float acc0[8], acc1[8];
#pragma unroll
    for (int n = 0; n < 8; ++n) { acc0[n] = 0.f; acc1[n] = 0.f; }
    const float4* w04 = (const float4*)(W + ch0 * 64);
    const float4* w14 = (const float4*)(W + ch1 * 64);
    for (int c4 = 0; c4 < 16; ++c4) {
        float4 wa = w04[c4];
        float4 wb = w14[c4];
#pragma unroll
        for (int n = 0; n < 8; ++n) {
            float4 hv = *(const float4*)&xs[(wv * 8 + n) * 64 + c4 * 4];
            acc0[n] += wa.x * hv.x + wa.y * hv.y + wa.z * hv.z + wa.w * hv.w;
            acc1[n] += wb.x * hv.x + wb.y * hv.y + wb.z * hv.z + wb.w * hv.w;
        }
    }
    const float b0 = b[ch0];
    const float b1 = b[ch1];
#pragma unroll
    for (int n = 0; n < 8; ++n) {
        int node = base + wv * 8 + n;
        if (node < N) {
            h[(size_t)node * 128 + ch0] = fmaxf(acc0[n] + b0, 0.f);
            h[(size_t)node * 128 + ch1] = fmaxf(acc1[n] + b1, 0.f);
        }
    }
}

__global__ void k_hist(const int* __restrict__ ei, int* __restrict__ cnt, int E, int EP) {
    int e = blockIdx.x * blockDim.x + threadIdx.x;
    if (e >= EP) return;
    int d_ = (e < E) ? ei[E + e] : e - E;
    atomicAdd(&cnt[d_], 1);
}

__global__ void k_scan(const int* __restrict__ cnt, int* __restrict__ off,
                       int* __restrict__ cur, int N) {
    __shared__ int tot[1024];
    const int t = threadIdx.x;
    const int chunk = (N + 1023) >> 10;
    const int s0 = t * chunk;
    const int s1 = min(s0 + chunk, N);
    int sum = 0;
    for (int i = s0; i < s1; ++i) sum += cnt[i];
    tot[t] = sum;
    __syncthreads();
    for (int d = 1; d < 1024; d <<= 1) {
        int v = (t >= d) ? tot[t - d] : 0;
        __syncthreads();
        tot[t] += v;
        __syncthreads();
    }
    int run = (t == 0) ? 0 : tot[t - 1];
    for (int i = s0; i < s1; ++i) {
        off[i] = run; cur[i] = run;
        run += cnt[i];
    }
}

// entangle circuit + linear/x_comb/q/k. Blocks [0,eblf): fill role (layer 0
// only). sprev: previous layer's sumexp (nullptr for layer 0) — h is stored
// UN-normalized by k_gather, the 1/S scale is applied when staging.
// Main GEMM blocking: thread owns 4 channels (c, c+32, c+64, c+96) x 4 nodes;
// each hs b128 read feeds 4 channel-accumulators (halves LDS issues vs 2ch).
#define HS_STRIDE 132
__global__ void k_entlin(const float* __restrict__ h, const float* __restrict__ rotE2,
                         const float* __restrict__ linW, const float* __restrict__ linb,
                         const float* __restrict__ qpW, const float* __restrict__ qpb,
                         const float* __restrict__ aqW, const float* __restrict__ aqb,
                         const float* __restrict__ akW, const float* __restrict__ akb,
                         float* __restrict__ xcomb, float* __restrict__ qbuf,
                         float* __restrict__ kbuf, int N,
                         const float* __restrict__ sprev,
                         int eblf, const int* __restrict__ ei,
                         int* __restrict__ cur, int* __restrict__ srcs,
                         int* __restrict__ inv, int E, int EP) {
    __shared__ float hs[16 * HS_STRIDE];
    __shared__ float xqs[16 * 4];
    const int tid = threadIdx.x;  // 128
    if (blockIdx.x < eblf) {
        // -------- fill role (counting-sort scatter) --------
        int e = blockIdx.x * 128 + tid;
        if (e < EP) {
            int s_, d_;
            if (e < E) { s_ = ei[e]; d_ = ei[E + e]; } else { s_ = d_ = e - E; }
            int pos = atomicAdd(&cur[d_], 1);
            srcs[pos] = s_;
            inv[e] = pos;
        }
        return;
    }
    const int base = (blockIdx.x - eblf) * 16;
    const float scale = sprev ? __builtin_amdgcn_rcpf(sprev[0]) : 1.0f;
    // stage h tile (float4, padded rows keep 16B alignment), scaled by 1/S
    for (int idx = tid; idx < 16 * 32; idx += 128) {
        int n = idx >> 5, c4 = idx & 31;
        int node = base + n;
        float4 hv = (node < N) ? *(const float4*)&h[(size_t)node * 128 + c4 * 4]
                               : make_float4(0.f, 0.f, 0.f, 0.f);
        hv.x *= scale; hv.y *= scale; hv.z *= scale; hv.w *= scale;
        *(float4*)&hs[n * HS_STRIDE + c4 * 4] = hv;
    }
    __syncthreads();
    if (tid < 64) {
        // wave 0: q/k dots. 128 dots = (node 0..15) x (which 0..7); 2 per lane.
#pragma unroll
        for (int rep = 0; rep < 2; ++rep) {
            const int dt = tid + rep * 64;
            const int nl = dt >> 3;
            const int which = dt & 7;
            const int qi = which & 3;
            const float4* Wp4 = (const float4*)(((which < 4) ? aqW : akW) + qi * 128);
            float dot = (which < 4) ? aqb[qi] : akb[qi];
            for (int c4 = 0; c4 < 32; ++c4) {
                float4 w = Wp4[c4];
                float4 hv = *(const float4*)&hs[nl * HS_STRIDE + c4 * 4];
                dot += w.x * hv.x + w.y * hv.y + w.z * hv.z + w.w * hv.w;
            }
            int node = base + nl;
            if (node < N) {
                float halfang = fast_tanh(dot) * (0.5f * PI_HALF);
                float s, c; __sincosf(halfang, &s, &c);
                float* dst = ((which < 4) ? qbuf : kbuf) + (size_t)node * 8 + qi * 2;
                dst[0] = c; dst[1] = s;
            }
        }
    } else if (tid < 80) {
        // wave 1 lanes 0-15: entangle circuit (real until first Rot).
        const int nl = tid - 64;
        if (base + nl < N) {
            float4 hv = *(const float4*)&hs[nl * HS_STRIDE];
            float c0, s0, c1, s1, c2, s2, c3, s3;
            { float a = fast_tanh(hv.x) * (0.5f * PI_HALF); __sincosf(a, &s0, &c0); }
            { float a = fast_tanh(hv.y) * (0.5f * PI_HALF); __sincosf(a, &s1, &c1); }
            { float a = fast_tanh(hv.z) * (0.5f * PI_HALF); __sincosf(a, &s2, &c2); }
            { float a = fast_tanh(hv.w) * (0.5f * PI_HALF); __sincosf(a, &s3, &c3); }
            float sr[16], si[16];
            prod_init(sr, c0, s0, c1, s1, c2, s2, c3, s3);
            cnot_r<8, 4>(sr); cnot_r<4, 2>(sr); cnot_r<2, 1>(sr);
            rot_first<8>(sr, si, rotE2);
            rot_pre<4>(sr, si, rotE2 + 8);
            rot_pre<2>(sr, si, rotE2 + 16);
            rot_pre<1>(sr, si, rotE2 + 24);
            cnot_g<8, 1>(sr, si);
            cnot_g<8, 4>(sr, si); cnot_g<4, 2>(sr, si); cnot_g<2, 1>(sr, si);
            const float* P = rotE2 + 32;
            rot_pre<8>(sr, si, P);
            rot_pre<4>(sr, si, P + 8);
            rot_pre<2>(sr, si, P + 16);
            rot_pre<1>(sr, si, P + 24);
            cnot_g<8, 1>(sr, si);
            float z[4]; zexp_g(sr, si, z);
            xqs[nl * 4 + 0] = z[0]; xqs[nl * 4 + 1] = z[1];
            xqs[nl * 4 + 2] = z[2]; xqs[nl * 4 + 3] = z[3];
        }
    }
    __syncthreads();
    // main GEMM: ng = tid>>5 -> nodes ng*4..+3; c = tid&31 -> ch c+{0,32,64,96}.
    const int ng = tid >> 5;
    const int c  = tid & 31;
    float acc[4][4];
#pragma unroll
    for (int n = 0; n < 4; ++n)
#pragma unroll
        for (int j = 0; j < 4; ++j) acc[n][j] = 0.f;
    const float4* wp0 = (const float4*)(linW + (c)      * 128);
    const float4* wp1 = (const float4*)(linW + (c + 32) * 128);
    const float4* wp2 = (const float4*)(linW + (c + 64) * 128);
    const float4* wp3 = (const float4*)(linW + (c + 96) * 128);
    for (int c4 = 0; c4 < 32; ++c4) {
        float4 w0 = wp0[c4], w1 = wp1[c4], w2 = wp2[c4], w3 = wp3[c4];
#pragma unroll
        for (int n = 0; n < 4; ++n) {
            float4 hv = *(const float4*)&hs[(ng * 4 + n) * HS_STRIDE + c4 * 4];
            acc[n][0] += w0.x * hv.x + w0.y * hv.y + w0.z * hv.z + w0.w * hv.w;
            acc[n][1] += w1.x * hv.x + w1.y * hv.y + w1.z * hv.z + w1.w * hv.w;
            acc[n][2] += w2.x * hv.x + w2.y * hv.y + w2.z * hv.z + w2.w * hv.w;
            acc[n][3] += w3.x * hv.x + w3.y * hv.y + w3.z * hv.z + w3.w * hv.w;
        }
    }
#pragma unroll
    for (int n = 0; n < 4; ++n) {
        const int nl = ng * 4 + n;
        const int node = base + nl;
        if (node < N) {
            float x0 = xqs[nl * 4 + 0], x1 = xqs[nl * 4 + 1];
            float x2 = xqs[nl * 4 + 2], x3 = xqs[nl * 4 + 3];
#pragma unroll
            for (int j = 0; j < 4; ++j) {
                const int ch = c + j * 32;
                xcomb[(size_t)node * 128 + ch] = acc[n][j] + linb[ch] + qpb[ch]
                    + qpW[ch * 4 + 0] * x0 + qpW[ch * 4 + 1] * x1
                    + qpW[ch * 4 + 2] * x2 + qpW[ch * 4 + 3] * x3;
            }
        }
    }
}

// attention circuit per edge (dense, full lane occupancy). Writes exp(score)
// slot-ordered via inv[]; block-reduces partial sum of exp into sumexp[l].
__global__ void k_att(const float* __restrict__ qb, const float* __restrict__ kb,
                      const int* __restrict__ ei, const float* __restrict__ RA,
                      const int* __restrict__ inv, float* __restrict__ escore,
                      float* __restrict__ sumexp, int E, int EP) {
    __shared__ float red[4];
    int e = blockIdx.x * blockDim.x + threadIdx.x;
    float ex = 0.f;
    if (e < EP) {
        int s_, d_;
        if (e < E) { s_ = ei[e]; d_ = ei[E + e]; } else { s_ = d_ = e - E; }
        float4 qa = *(const float4*)&qb[(size_t)s_ * 8];
        float4 qc = *(const float4*)&qb[(size_t)s_ * 8 + 4];
        float4 ka = *(const float4*)&kb[(size_t)d_ * 8];
        float4 kc = *(const float4*)&kb[(size_t)d_ * 8 + 4];
        float sr[16], si[16];
        prod_init(sr, qa.x, qa.y, qa.z, qa.w, qc.x, qc.y, qc.z, qc.w);
        had_r<8>(sr); had_r<4>(sr); had_r<2>(sr); had_r<1>(sr);
        cry_r<8, 4>(sr, ka.x, ka.y);
        cry_r<4, 2>(sr, ka.z, ka.w);
        cry_r<2, 1>(sr, kc.x, kc.y);
        cry_r<1, 8>(sr, kc.z, kc.w);
        rot_first<8>(sr, si, RA);
        rot_pre<4>(sr, si, RA + 8);
        rot_pre<2>(sr, si, RA + 16);
        rot_pre<1>(sr, si, RA + 24);
        float p0  = sr[0]  * sr[0]  + si[0]  * si[0];
        float p1  = sr[1]  * sr[1]  + si[1]  * si[1];
        float p2  = sr[2]  * sr[2]  + si[2]  * si[2];
        float p4  = sr[4]  * sr[4]  + si[4]  * si[4];
        float p8  = sr[8]  * sr[8]  + si[8]  * si[8];
        float p7  = sr[7]  * sr[7]  + si[7]  * si[7];
        float p11 = sr[11] * sr[11] + si[11] * si[11];
        float p13 = sr[13] * sr[13] + si[13] * si[13];
        float p14 = sr[14] * sr[14] + si[14] * si[14];
        float p15 = sr[15] * sr[15] + si[15] * si[15];
        float sc = (p0 - p15) + 0.5f * ((p1 + p2 + p4 + p8) - (p7 + p11 + p13 + p14));
        ex = __expf(sc);
        escore[inv[e]] = ex;
    }
    float wsum = ex;
#pragma unroll
    for (int d = 32; d; d >>= 1) wsum += __shfl_xor(wsum, d, 64);
    if ((threadIdx.x & 63) == 0) red[threadIdx.x >> 6] = wsum;
    __syncthreads();
    if (threadIdx.x == 0) atomicAdd(sumexp, red[0] + red[1] + red[2] + red[3]);
}

// one block per dst: h_raw[d,:] = relu(sum escore*xcomb[src,:]) (un-normalized;
// 1/S applied downstream since relu(x)/S == relu(x/S) for S>0).
// ILP-8 batched loads: the scattered xcomb rows hit L2/L3 at ~600cy latency;
// 8 independent loads in flight cut the serial chain 8x.
__global__ void k_gather(const float* __restrict__ xcomb, const int* __restrict__ srcs,
                         const float* __restrict__ escore, const int* __restrict__ off,
                         const int* __restrict__ cnt, float* __restrict__ h) {
    __shared__ int sS[128];
    __shared__ float wS[128];
    const int b = blockIdx.x;
    const int tid = threadIdx.x;  // 128
    const int start = off[b];
    const int num = cnt[b];
    float acc = 0.f;
    for (int base = 0; base < num; base += 128) {
        int m = min(128, num - base);
        if (tid < m) {
            sS[tid] = srcs[start + base + tid];
            wS[tid] = escore[start + base + tid];
        }
        __syncthreads();
        int i = 0;
        for (; i + 8 <= m; i += 8) {
            float v0 = xcomb[(size_t)sS[i + 0] * 128 + tid];
            float v1 = xcomb[(size_t)sS[i + 1] * 128 + tid];
            float v2 = xcomb[(size_t)sS[i + 2] * 128 + tid];
            float v3 = xcomb[(size_t)sS[i + 3] * 128 + tid];
            float v4 = xcomb[(size_t)sS[i + 4] * 128 + tid];
            float v5 = xcomb[(size_t)sS[i + 5] * 128 + tid];
            float v6 = xcomb[(size_t)sS[i + 6] * 128 + tid];
            float v7 = xcomb[(size_t)sS[i + 7] * 128 + tid];
            // sequential adds keep the original accumulation order
            acc += wS[i + 0] * v0; acc += wS[i + 1] * v1;
            acc += wS[i + 2] * v2; acc += wS[i + 3] * v3;
            acc += wS[i + 4] * v4; acc += wS[i + 5] * v5;
            acc += wS[i + 6] * v6; acc += wS[i + 7] * v7;
        }
        for (; i < m; ++i)
            acc += wS[i] * xcomb[(size_t)sS[i] * 128 + tid];
        __syncthreads();
    }
    h[(size_t)b * 128 + tid] = fmaxf(acc, 0.f);
}

// fused tail: path_in projection + path circuit + epilogue out = M@z + v.
// h is un-normalized (layer-1 gather output); 1/S folds into the raw dot.
__global__ void k_tail(const float* __restrict__ h, const float* __restrict__ piW,
                       const float* __restrict__ pib, const float* __restrict__ RP,
                       const float* __restrict__ M, const float* __restrict__ v,
                       const float* __restrict__ sprev,
                       float* __restrict__ out, int N) {
    __shared__ float pqS[64 * 8];
    __shared__ float zS[64 * 4];
    __shared__ float MS[128];
    __shared__ float vS[32];
    const int tid = threadIdx.x;  // 256
    const int base = blockIdx.x * 64;
    if (tid < 128) MS[tid] = M[tid];
    else if (tid < 160) vS[tid - 128] = v[tid - 128];
    const float invS = __builtin_amdgcn_rcpf(sprev[0]);
    // phase 1: one projection dot per thread
    {
        const int nl = tid >> 2, i = tid & 3;
        const int node = base + nl;
        if (node < N) {
            float raw = 0.f;
            const float4* w4 = (const float4*)(piW + i * 128);
            const float4* h4 = (const float4*)(h + (size_t)node * 128);
#pragma unroll 8
            for (int c4 = 0; c4 < 32; ++c4) {
                float4 w = w4[c4];
                float4 hv = h4[c4];
                raw += w.x * hv.x + w.y * hv.y + w.z * hv.z + w.w * hv.w;
            }
            float dot = pib[i] + invS * raw;
            float halfang = fast_tanh(dot) * (0.5f * PI_HALF);
            float s, c; __sincosf(halfang, &s, &c);
            pqS[nl * 8 + i * 2]     = c;
            pqS[nl * 8 + i * 2 + 1] = s;
        }
    }
    __syncthreads();
    // phase 2: path circuit, one node per lane (lanes 0-63).
    if (tid < 64 && base + tid < N) {
        const float r = 0.70710678118654752f;
        float c0 = pqS[tid * 8 + 0], s0 = pqS[tid * 8 + 1];
        float c1 = pqS[tid * 8 + 2], s1 = pqS[tid * 8 + 3];
        float c2 = pqS[tid * 8 + 4], s2 = pqS[tid * 8 + 5];
        float c3 = pqS[tid * 8 + 6], s3 = pqS[tid * 8 + 7];
        float u0 = r * (c0 - s0), w0 = r * (c0 + s0);
        float u1 = r * (c1 - s1), w1 = r * (c1 + s1);
        float u2 = r * (c2 - s2), w2 = r * (c2 + s2);
        float u3 = r * (c3 - s3), w3 = r * (c3 + s3);
        float sr[16], si[16];
        prod_init(sr, u0, w0, u1, w1, u2, w2, u3, w3);
        rot_first<8>(sr, si, RP);
        rot_pre<4>(sr, si, RP + 8);
        rot_pre<2>(sr, si, RP + 16);
        rot_pre<1>(sr, si, RP + 24);
        cnot_g<8, 4>(sr, si); cnot_g<4, 2>(sr, si); cnot_g<2, 1>(sr, si);
#pragma unroll
        for (int l = 1; l < 3; ++l) {
            const float* P = RP + l * 32;
            rot_pre<8>(sr, si, P);
            rot_pre<4>(sr, si, P + 8);
            rot_pre<2>(sr, si, P + 16);
            rot_pre<1>(sr, si, P + 24);
            cnot_g<8, 4>(sr, si); cnot_g<4, 2>(sr, si); cnot_g<2, 1>(sr, si);
        }
        float z[4]; zexp_g(sr, si, z);
        zS[tid * 4 + 0] = z[0]; zS[tid * 4 + 1] = z[1];
        zS[tid * 4 + 2] = z[2]; zS[tid * 4 + 3] = z[3];
    }
    __syncthreads();
    // phase 3: epilogue, 64 nodes x 32 outputs, coalesced
#pragma unroll
    for (int k = 0; k < 8; ++k) {
        int flat = k * 256 + tid;
        int nl = flat >> 5;
        int o = flat & 31;
        int node = base + nl;
        if (node < N) {
            out[(size_t)node * 32 + o] = vS[o]
                + MS[o * 4 + 0] * zS[nl * 4 + 0] + MS[o * 4 + 1] * zS[nl * 4 + 1]
                + MS[o * 4 + 2] * zS[nl * 4 + 2] + MS[o * 4 + 3] * zS[nl * 4 + 3];
        }
    }
}

// ---------------- launch ----------------------------------------------------

extern "C" void kernel_launch(void* const* d_in, const int* in_sizes, int n_in,
                              void* d_out, int out_size, void* d_ws, size_t ws_size,
                              hipStream_t stream) {
    const float* x     = (const float*)d_in[0];
    const float* W_in  = (const float*)d_in[1];
    const float* b_in  = (const float*)d_in[2];
    const float* linW  = (const float*)d_in[3];
    const float* linb  = (const float*)d_in[4];
    const float* qpW   = (const float*)d_in[5];
    const float* qpb   = (const float*)d_in[6];
    const float* entp  = (const float*)d_in[7];
    const float* aqW   = (const float*)d_in[8];
    const float* aqb   = (const float*)d_in[9];
    const float* akW   = (const float*)d_in[10];
    const float* akb   = (const float*)d_in[11];
    const float* attqp = (const float*)d_in[12];
    const float* pparm = (const float*)d_in[13];
    const float* piW   = (const float*)d_in[14];
    const float* pib   = (const float*)d_in[15];
    const float* poW   = (const float*)d_in[16];
    const float* pob   = (const float*)d_in[17];
    const float* outW  = (const float*)d_in[18];
    const float* outb  = (const float*)d_in[19];
    const int*   ei    = (const int*)d_in[20];

    const int N  = in_sizes[0] / 64;   // 20000
    const int E  = in_sizes[20] / 2;   // 300000
    const int EP = E + N;              // self-loops appended

    float* ws     = (float*)d_ws;
    float* h      = ws;
    float* xcomb  = h      + (size_t)N * 128;
    float* qbuf   = xcomb  + (size_t)N * 128;
    float* kbuf   = qbuf   + (size_t)N * 8;
    float* escore = kbuf   + (size_t)N * 8;
    float* rotbuf = escore + EP;
    float* Mm     = rotbuf + 36 * 8;
    float* vv     = Mm + 128;
    int*   cnt    = (int*)(vv + 32);
    float* sumexp = (float*)(cnt + N);   // 4 slots
    int*   off    = (int*)(sumexp + 4);
    int*   cur    = off + N;
    int*   srcs   = cur + N;
    int*   inv    = srcs + EP;

    const float* rotE = rotbuf;          // 16 matrices
    const float* rotA = rotbuf + 128;    // 8 matrices
    const float* rotP = rotbuf + 192;    // 12 matrices

    const int nb16 = (N + 15) / 16;
    const int nb32 = (N + 31) / 32;
    const int ebl  = (EP + 255) / 256;
    const int eblf = (EP + 127) / 128;

    // 1: zero(cnt,sumexp) + setup + input GEMM
    k_fsi<<<nb32 + 1, 256, 0, stream>>>(entp, attqp, pparm, outW, outb, poW, pob,
                                        rotbuf, Mm, vv, x, W_in, b_in, h,
                                        cnt, sumexp, N);
    // 2: histogram of dsts
    k_hist<<<ebl, 256, 0, stream>>>(ei, cnt, E, EP);
    // 3: exclusive scan
    k_scan<<<1, 1024, 0, stream>>>(cnt, off, cur, N);

    for (int l = 0; l < 2; ++l) {
        const int fillb = (l == 0) ? eblf : 0;
        // 4/7: fill (layer 0 only) + entangle + linear + q/k
        k_entlin<<<fillb + nb16, 128, 0, stream>>>(h, rotE + l * 64,
            linW + (size_t)l * 128 * 128, linb + l * 128,
            qpW + (size_t)l * 128 * 4, qpb + l * 128,
            aqW + (size_t)l * 4 * 128, aqb + l * 4,
            akW + (size_t)l * 4 * 128, akb + l * 4,
            xcomb, qbuf, kbuf, N,
            (l == 0) ? (const float*)nullptr : (const float*)(sumexp + 0),
            fillb, ei, cur, srcs, inv, E, EP);
        // 5/8: dense per-edge attention circuits
        k_att<<<ebl, 256, 0, stream>>>(qbuf, kbuf, ei, rotA + l * 32, inv,
                                       escore, sumexp + l, E, EP);
        // 6/9: per-dst gather (un-normalized, ILP-8)
        k_gather<<<N, 128, 0, stream>>>(xcomb, srcs, escore, off, cnt, h);
    }

    // 10: tail with 1/S fold
    k_tail<<<(N + 63) / 64, 256, 0, stream>>>(h, piW, pib, rotP, Mm, vv,
                                              sumexp + 1, (float*)d_out, N);
}

// Round 8
// 368.971 us; speedup vs baseline: 8.1300x; 1.1268x over previous
//
#include <hip/hip_runtime.h>
#include <math.h>

#define PI_HALF 1.57079632679489662f

__device__ __forceinline__ float fast_tanh(float x) {
    float e = __expf(2.f * x);
    return 1.f - 2.f * __builtin_amdgcn_rcpf(e + 1.f);
}

// ---------------- 4-qubit state helpers (compile-time masks -> registers) ----
// wire w (0..3) maps to amplitude-index bit (3-w), i.e. mask = 8 >> w.

__device__ __forceinline__ void prod_init(float sr[16],
        float c0, float s0, float c1, float s1,
        float c2, float s2, float c3, float s3) {
    float p2[4];
    p2[0] = c0 * c1; p2[1] = c0 * s1; p2[2] = s0 * c1; p2[3] = s0 * s1;
    float p3[8];
#pragma unroll
    for (int j = 0; j < 4; ++j) { p3[2 * j] = p2[j] * c2; p3[2 * j + 1] = p2[j] * s2; }
#pragma unroll
    for (int j = 0; j < 8; ++j) { sr[2 * j] = p3[j] * c3; sr[2 * j + 1] = p3[j] * s3; }
}

template<int M>
__device__ __forceinline__ void had_r(float sr[16]) {
    const float r = 0.70710678118654752f;
#pragma unroll
    for (int i = 0; i < 16; ++i) {
        if (i & M) continue;
        const int j = i | M;
        float ar = sr[i], br = sr[j];
        sr[i] = (ar + br) * r;
        sr[j] = (ar - br) * r;
    }
}

template<int MC, int MT>
__device__ __forceinline__ void cry_r(float sr[16], float c, float s) {
#pragma unroll
    for (int i = 0; i < 16; ++i) {
        if (!(i & MC) || (i & MT)) continue;
        const int j = i | MT;
        float ar = sr[i], br = sr[j];
        sr[i] = c * ar - s * br;
        sr[j] = s * ar + c * br;
    }
}

template<int MC, int MT>
__device__ __forceinline__ void cnot_r(float sr[16]) {
#pragma unroll
    for (int i = 0; i < 16; ++i) {
        if (!(i & MC) || (i & MT)) continue;
        const int j = i | MT;
        float t = sr[i]; sr[i] = sr[j]; sr[j] = t;
    }
}

template<int MC, int MT>
__device__ __forceinline__ void cnot_g(float sr[16], float si[16]) {
#pragma unroll
    for (int i = 0; i < 16; ++i) {
        if (!(i & MC) || (i & MT)) continue;
        const int j = i | MT;
        float tr = sr[i], ti = si[i];
        sr[i] = sr[j]; si[i] = si[j];
        sr[j] = tr;    si[j] = ti;
    }
}

template<int M>
__device__ __forceinline__ void rot_pre(float sr[16], float si[16], const float* __restrict__ u) {
    const float u00r = u[0], u00i = u[1], u01r = u[2], u01i = u[3];
    const float u10r = u[4], u10i = u[5], u11r = u[6], u11i = u[7];
#pragma unroll
    for (int i = 0; i < 16; ++i) {
        if (i & M) continue;
        const int j = i | M;
        float ar = sr[i], ai = si[i], br = sr[j], bi = si[j];
        sr[i] = u00r * ar - u00i * ai + u01r * br - u01i * bi;
        si[i] = u00r * ai + u00i * ar + u01r * bi + u01i * br;
        sr[j] = u10r * ar - u10i * ai + u11r * br - u11i * bi;
        si[j] = u10r * ai + u10i * ar + u11r * bi + u11i * br;
    }
}

// first Rot applied to a purely-real state (si implicitly 0); bitwise-identical
// to rot_pre with ai=bi=0 (dropped terms are exact zeros).
template<int M>
__device__ __forceinline__ void rot_first(float sr[16], float si[16], const float* __restrict__ u) {
    const float u00r = u[0], u00i = u[1], u01r = u[2], u01i = u[3];
    const float u10r = u[4], u10i = u[5], u11r = u[6], u11i = u[7];
#pragma unroll
    for (int i = 0; i < 16; ++i) {
        if (i & M) continue;
        const int j = i | M;
        float ar = sr[i], br = sr[j];
        sr[i] = u00r * ar + u01r * br;
        si[i] = u00i * ar + u01i * br;
        sr[j] = u10r * ar + u11r * br;
        si[j] = u10i * ar + u11i * br;
    }
}

__device__ __forceinline__ void zexp_g(const float sr[16], const float si[16], float z[4]) {
    float p[16];
#pragma unroll
    for (int i = 0; i < 16; ++i) p[i] = sr[i] * sr[i] + si[i] * si[i];
    z[0] = z[1] = z[2] = z[3] = 0.f;
#pragma unroll
    for (int i = 0; i < 16; ++i) {
        z[0] += (i & 8) ? -p[i] : p[i];
        z[1] += (i & 4) ? -p[i] : p[i];
        z[2] += (i & 2) ? -p[i] : p[i];
        z[3] += (i & 1) ? -p[i] : p[i];
    }
}

// ---------------- kernels ---------------------------------------------------

// k_fsi: zero cnt/sumexp (completes at kernel boundary, before k_hist's atomics)
// + setup (block 0) + input GEMM h = relu(x @ W_in^T + b_in) (blocks 1..).
// GEMM blocking: wave w owns nodes w*8..w*8+7; lane owns ch=lane, lane+64 so
// each xs b128 broadcast feeds 2 channel-accumulators; stores are 256B-contiguous.
__global__ void k_fsi(const float* __restrict__ entp, const float* __restrict__ attqp,
                      const float* __restrict__ pparm,
                      const float* __restrict__ outW, const float* __restrict__ outb,
                      const float* __restrict__ poW, const float* __restrict__ pob,
                      float* __restrict__ rotbuf, float* __restrict__ M,
                      float* __restrict__ v,
                      const float* __restrict__ x, const float* __restrict__ W,
                      const float* __restrict__ b, float* __restrict__ h,
                      int* __restrict__ cnt, float* __restrict__ sumexp, int N) {
    __shared__ float xs[32 * 64];
    const int bb = blockIdx.x;
    const int tid = threadIdx.x;  // 256
    // zero role: grid-strided cnt + sumexp (hist runs in the NEXT kernel)
    {
        const int gid = bb * 256 + tid;
        const int T = gridDim.x * 256;
        for (int i = gid; i < N; i += T) cnt[i] = 0;
        if (gid < 4) sumexp[gid] = 0.f;
    }
    if (bb == 0) {
        // -------- setup role: rot matrices + fused output matrix --------
        const int t = tid;
        if (t < 36) {
            const float* p;
            if (t < 16)      p = entp  + t * 3;
            else if (t < 24) p = attqp + (t - 16) * 3;
            else             p = pparm + (t - 24) * 3;
            float phi = p[0], theta = p[1], omega = p[2];
            float st, ct; sincosf(0.5f * theta, &st, &ct);
            float sp, cp; sincosf(0.5f * (phi + omega), &sp, &cp);
            float sm, cm; sincosf(0.5f * (phi - omega), &sm, &cm);
            float* u = rotbuf + t * 8;
            u[0] =  ct * cp;  u[1] = -ct * sp;
            u[2] = -st * cm;  u[3] = -st * sm;
            u[4] =  st * cm;  u[5] = -st * sm;
            u[6] =  ct * cp;  u[7] =  ct * sp;
        } else if (t >= 64 && t < 192) {
            int t2 = t - 64;
            int o = t2 >> 2, i = t2 & 3;
            float acc = 0.f;
            for (int j = 0; j < 128; ++j) acc += outW[o * 128 + j] * poW[j * 4 + i];
            M[t2] = acc;
        } else if (t >= 192 && t < 224) {
            int o = t - 192;
            float acc = outb[o];
            for (int j = 0; j < 128; ++j) acc += outW[o * 128 + j] * pob[j];
            v[o] = acc;
        }
        return;
    }
    // -------- input-GEMM role: 32 nodes per block --------
    const int base = (bb - 1) * 32;
    for (int idx = tid; idx < 32 * 64; idx += 256) {
        int n = base + (idx >> 6);
        xs[idx] = (n < N) ? x[(size_t)n * 64 + (idx & 63)] : 0.f;
    }
    __syncthreads();
    const int lane = tid & 63;
    const int wv = tid >> 6;            // wave 0..3 -> nodes wv*8..wv*8+7
    const int ch0 = lane, ch1 = lane + 64;
    float acc0[8], acc1[8];
#pragma unroll
    for (int n = 0; n < 8; ++n) { acc0[n] = 0.f; acc1[n] = 0.f; }
    const float4* w04 = (const float4*)(W + ch0 * 64);
    const float4* w14 = (const float4*)(W + ch1 * 64);
    for (int c4 = 0; c4 < 16; ++c4) {
        float4 wa = w04[c4];
        float4 wb = w14[c4];
#pragma unroll
        for (int n = 0; n < 8; ++n) {
            float4 hv = *(const float4*)&xs[(wv * 8 + n) * 64 + c4 * 4];
            acc0[n] += wa.x * hv.x + wa.y * hv.y + wa.z * hv.z + wa.w * hv.w;
            acc1[n] += wb.x * hv.x + wb.y * hv.y + wb.z * hv.z + wb.w * hv.w;
        }
    }
    const float b0 = b[ch0];
    const float b1 = b[ch1];
#pragma unroll
    for (int n = 0; n < 8; ++n) {
        int node = base + wv * 8 + n;
        if (node < N) {
            h[(size_t)node * 128 + ch0] = fmaxf(acc0[n] + b0, 0.f);
            h[(size_t)node * 128 + ch1] = fmaxf(acc1[n] + b1, 0.f);
        }
    }
}

__global__ void k_hist(const int* __restrict__ ei, int* __restrict__ cnt, int E, int EP) {
    int e = blockIdx.x * blockDim.x + threadIdx.x;
    if (e >= EP) return;
    int d_ = (e < E) ? ei[E + e] : e - E;
    atomicAdd(&cnt[d_], 1);
}

__global__ void k_scan(const int* __restrict__ cnt, int* __restrict__ off,
                       int* __restrict__ cur, int N) {
    __shared__ int tot[1024];
    const int t = threadIdx.x;
    const int chunk = (N + 1023) >> 10;
    const int s0 = t * chunk;
    const int s1 = min(s0 + chunk, N);
    int sum = 0;
    for (int i = s0; i < s1; ++i) sum += cnt[i];
    tot[t] = sum;
    __syncthreads();
    for (int d = 1; d < 1024; d <<= 1) {
        int v = (t >= d) ? tot[t - d] : 0;
        __syncthreads();
        tot[t] += v;
        __syncthreads();
    }
    int run = (t == 0) ? 0 : tot[t - 1];
    for (int i = s0; i < s1; ++i) {
        off[i] = run; cur[i] = run;
        run += cnt[i];
    }
}

// entangle circuit + linear/x_comb/q/k. Blocks [0,eblf): fill role (layer 0
// only). sprev: previous layer's sumexp (nullptr for layer 0) — h is stored
// UN-normalized by k_gather, the 1/S scale is applied when staging.
// Main GEMM blocking (round-3-proven): wave nh owns nodes nh*8..+7; lane owns
// ch=lane, lane+64. Stores are 256B-contiguous per wave (no write amplification).
#define HS_STRIDE 132
__global__ void k_entlin(const float* __restrict__ h, const float* __restrict__ rotE2,
                         const float* __restrict__ linW, const float* __restrict__ linb,
                         const float* __restrict__ qpW, const float* __restrict__ qpb,
                         const float* __restrict__ aqW, const float* __restrict__ aqb,
                         const float* __restrict__ akW, const float* __restrict__ akb,
                         float* __restrict__ xcomb, float* __restrict__ qbuf,
                         float* __restrict__ kbuf, int N,
                         const float* __restrict__ sprev,
                         int eblf, const int* __restrict__ ei,
                         int* __restrict__ cur, int* __restrict__ srcs,
                         int* __restrict__ inv, int E, int EP) {
    __shared__ float hs[16 * HS_STRIDE];
    __shared__ float xqs[16 * 4];
    const int tid = threadIdx.x;  // 128
    if (blockIdx.x < eblf) {
        // -------- fill role (counting-sort scatter) --------
        int e = blockIdx.x * 128 + tid;
        if (e < EP) {
            int s_, d_;
            if (e < E) { s_ = ei[e]; d_ = ei[E + e]; } else { s_ = d_ = e - E; }
            int pos = atomicAdd(&cur[d_], 1);
            srcs[pos] = s_;
            inv[e] = pos;
        }
        return;
    }
    const int base = (blockIdx.x - eblf) * 16;
    const float scale = sprev ? __builtin_amdgcn_rcpf(sprev[0]) : 1.0f;
    // stage h tile (float4, padded rows keep 16B alignment), scaled by 1/S
    for (int idx = tid; idx < 16 * 32; idx += 128) {
        int n = idx >> 5, c4 = idx & 31;
        int node = base + n;
        float4 hv = (node < N) ? *(const float4*)&h[(size_t)node * 128 + c4 * 4]
                               : make_float4(0.f, 0.f, 0.f, 0.f);
        hv.x *= scale; hv.y *= scale; hv.z *= scale; hv.w *= scale;
        *(float4*)&hs[n * HS_STRIDE + c4 * 4] = hv;
    }
    __syncthreads();
    if (tid < 64) {
        // wave 0: q/k dots. 128 dots = (node 0..15) x (which 0..7); 2 per lane.
#pragma unroll
        for (int rep = 0; rep < 2; ++rep) {
            const int dt = tid + rep * 64;
            const int nl = dt >> 3;
            const int which = dt & 7;
            const int qi = which & 3;
            const float4* Wp4 = (const float4*)(((which < 4) ? aqW : akW) + qi * 128);
            float dot = (which < 4) ? aqb[qi] : akb[qi];
            for (int c4 = 0; c4 < 32; ++c4) {
                float4 w = Wp4[c4];
                float4 hv = *(const float4*)&hs[nl * HS_STRIDE + c4 * 4];
                dot += w.x * hv.x + w.y * hv.y + w.z * hv.z + w.w * hv.w;
            }
            int node = base + nl;
            if (node < N) {
                float halfang = fast_tanh(dot) * (0.5f * PI_HALF);
                float s, c; __sincosf(halfang, &s, &c);
                float* dst = ((which < 4) ? qbuf : kbuf) + (size_t)node * 8 + qi * 2;
                dst[0] = c; dst[1] = s;
            }
        }
    } else if (tid < 80) {
        // wave 1 lanes 0-15: entangle circuit (real until first Rot).
        const int nl = tid - 64;
        if (base + nl < N) {
            float4 hv = *(const float4*)&hs[nl * HS_STRIDE];
            float c0, s0, c1, s1, c2, s2, c3, s3;
            { float a = fast_tanh(hv.x) * (0.5f * PI_HALF); __sincosf(a, &s0, &c0); }
            { float a = fast_tanh(hv.y) * (0.5f * PI_HALF); __sincosf(a, &s1, &c1); }
            { float a = fast_tanh(hv.z) * (0.5f * PI_HALF); __sincosf(a, &s2, &c2); }
            { float a = fast_tanh(hv.w) * (0.5f * PI_HALF); __sincosf(a, &s3, &c3); }
            float sr[16], si[16];
            prod_init(sr, c0, s0, c1, s1, c2, s2, c3, s3);
            cnot_r<8, 4>(sr); cnot_r<4, 2>(sr); cnot_r<2, 1>(sr);
            rot_first<8>(sr, si, rotE2);
            rot_pre<4>(sr, si, rotE2 + 8);
            rot_pre<2>(sr, si, rotE2 + 16);
            rot_pre<1>(sr, si, rotE2 + 24);
            cnot_g<8, 1>(sr, si);
            cnot_g<8, 4>(sr, si); cnot_g<4, 2>(sr, si); cnot_g<2, 1>(sr, si);
            const float* P = rotE2 + 32;
            rot_pre<8>(sr, si, P);
            rot_pre<4>(sr, si, P + 8);
            rot_pre<2>(sr, si, P + 16);
            rot_pre<1>(sr, si, P + 24);
            cnot_g<8, 1>(sr, si);
            float z[4]; zexp_g(sr, si, z);
            xqs[nl * 4 + 0] = z[0]; xqs[nl * 4 + 1] = z[1];
            xqs[nl * 4 + 2] = z[2]; xqs[nl * 4 + 3] = z[3];
        }
    }
    __syncthreads();
    // main GEMM: wave nh handles nodes nh*8..nh*8+7; lane handles ch=lane, lane+64.
    const int lane = tid & 63;
    const int nh = tid >> 6;
    const int ch0 = lane, ch1 = lane + 64;
    float acc0[8], acc1[8];
#pragma unroll
    for (int n = 0; n < 8; ++n) { acc0[n] = 0.f; acc1[n] = 0.f; }
    const float4* w04 = (const float4*)(linW + ch0 * 128);
    const float4* w14 = (const float4*)(linW + ch1 * 128);
    for (int c4 = 0; c4 < 32; ++c4) {
        float4 wa = w04[c4];
        float4 wb = w14[c4];
#pragma unroll
        for (int n = 0; n < 8; ++n) {
            float4 hv = *(const float4*)&hs[(nh * 8 + n) * HS_STRIDE + c4 * 4];
            acc0[n] += wa.x * hv.x + wa.y * hv.y + wa.z * hv.z + wa.w * hv.w;
            acc1[n] += wb.x * hv.x + wb.y * hv.y + wb.z * hv.z + wb.w * hv.w;
        }
    }
    const float b0 = linb[ch0] + qpb[ch0];
    const float b1 = linb[ch1] + qpb[ch1];
    const float q00 = qpW[ch0 * 4 + 0], q01 = qpW[ch0 * 4 + 1];
    const float q02 = qpW[ch0 * 4 + 2], q03 = qpW[ch0 * 4 + 3];
    const float q10 = qpW[ch1 * 4 + 0], q11 = qpW[ch1 * 4 + 1];
    const float q12 = qpW[ch1 * 4 + 2], q13 = qpW[ch1 * 4 + 3];
#pragma unroll
    for (int n = 0; n < 8; ++n) {
        const int nl = nh * 8 + n;
        const int node = base + nl;
        if (node < N) {
            float x0 = xqs[nl * 4 + 0], x1 = xqs[nl * 4 + 1];
            float x2 = xqs[nl * 4 + 2], x3 = xqs[nl * 4 + 3];
            xcomb[(size_t)node * 128 + ch0] = acc0[n] + b0
                + q00 * x0 + q01 * x1 + q02 * x2 + q03 * x3;
            xcomb[(size_t)node * 128 + ch1] = acc1[n] + b1
                + q10 * x0 + q11 * x1 + q12 * x2 + q13 * x3;
        }
    }
}

// attention circuit per edge (dense, full lane occupancy). Writes exp(score)
// slot-ordered via inv[]; block-reduces partial sum of exp into sumexp[l].
__global__ void k_att(const float* __restrict__ qb, const float* __restrict__ kb,
                      const int* __restrict__ ei, const float* __restrict__ RA,
                      const int* __restrict__ inv, float* __restrict__ escore,
                      float* __restrict__ sumexp, int E, int EP) {
    __shared__ float red[4];
    int e = blockIdx.x * blockDim.x + threadIdx.x;
    float ex = 0.f;
    if (e < EP) {
        int s_, d_;
        if (e < E) { s_ = ei[e]; d_ = ei[E + e]; } else { s_ = d_ = e - E; }
        float4 qa = *(const float4*)&qb[(size_t)s_ * 8];
        float4 qc = *(const float4*)&qb[(size_t)s_ * 8 + 4];
        float4 ka = *(const float4*)&kb[(size_t)d_ * 8];
        float4 kc = *(const float4*)&kb[(size_t)d_ * 8 + 4];
        float sr[16], si[16];
        prod_init(sr, qa.x, qa.y, qa.z, qa.w, qc.x, qc.y, qc.z, qc.w);
        had_r<8>(sr); had_r<4>(sr); had_r<2>(sr); had_r<1>(sr);
        cry_r<8, 4>(sr, ka.x, ka.y);
        cry_r<4, 2>(sr, ka.z, ka.w);
        cry_r<2, 1>(sr, kc.x, kc.y);
        cry_r<1, 8>(sr, kc.z, kc.w);
        rot_first<8>(sr, si, RA);
        rot_pre<4>(sr, si, RA + 8);
        rot_pre<2>(sr, si, RA + 16);
        rot_pre<1>(sr, si, RA + 24);
        float p0  = sr[0]  * sr[0]  + si[0]  * si[0];
        float p1  = sr[1]  * sr[1]  + si[1]  * si[1];
        float p2  = sr[2]  * sr[2]  + si[2]  * si[2];
        float p4  = sr[4]  * sr[4]  + si[4]  * si[4];
        float p8  = sr[8]  * sr[8]  + si[8]  * si[8];
        float p7  = sr[7]  * sr[7]  + si[7]  * si[7];
        float p11 = sr[11] * sr[11] + si[11] * si[11];
        float p13 = sr[13] * sr[13] + si[13] * si[13];
        float p14 = sr[14] * sr[14] + si[14] * si[14];
        float p15 = sr[15] * sr[15] + si[15] * si[15];
        float sc = (p0 - p15) + 0.5f * ((p1 + p2 + p4 + p8) - (p7 + p11 + p13 + p14));
        ex = __expf(sc);
        escore[inv[e]] = ex;
    }
    float wsum = ex;
#pragma unroll
    for (int d = 32; d; d >>= 1) wsum += __shfl_xor(wsum, d, 64);
    if ((threadIdx.x & 63) == 0) red[threadIdx.x >> 6] = wsum;
    __syncthreads();
    if (threadIdx.x == 0) atomicAdd(sumexp, red[0] + red[1] + red[2] + red[3]);
}

// one block per dst: h_raw[d,:] = relu(sum escore*xcomb[src,:]) (un-normalized;
// 1/S applied downstream since relu(x)/S == relu(x/S) for S>0).
// ILP-8 batched loads keep 8 scattered xcomb lines in flight.
__global__ void k_gather(const float* __restrict__ xcomb, const int* __restrict__ srcs,
                         const float* __restrict__ escore, const int* __restrict__ off,
                         const int* __restrict__ cnt, float* __restrict__ h) {
    __shared__ int sS[128];
    __shared__ float wS[128];
    const int b = blockIdx.x;
    const int tid = threadIdx.x;  // 128
    const int start = off[b];
    const int num = cnt[b];
    float acc = 0.f;
    for (int base = 0; base < num; base += 128) {
        int m = min(128, num - base);
        if (tid < m) {
            sS[tid] = srcs[start + base + tid];
            wS[tid] = escore[start + base + tid];
        }
        __syncthreads();
        int i = 0;
        for (; i + 8 <= m; i += 8) {
            float v0 = xcomb[(size_t)sS[i + 0] * 128 + tid];
            float v1 = xcomb[(size_t)sS[i + 1] * 128 + tid];
            float v2 = xcomb[(size_t)sS[i + 2] * 128 + tid];
            float v3 = xcomb[(size_t)sS[i + 3] * 128 + tid];
            float v4 = xcomb[(size_t)sS[i + 4] * 128 + tid];
            float v5 = xcomb[(size_t)sS[i + 5] * 128 + tid];
            float v6 = xcomb[(size_t)sS[i + 6] * 128 + tid];
            float v7 = xcomb[(size_t)sS[i + 7] * 128 + tid];
            acc += wS[i + 0] * v0; acc += wS[i + 1] * v1;
            acc += wS[i + 2] * v2; acc += wS[i + 3] * v3;
            acc += wS[i + 4] * v4; acc += wS[i + 5] * v5;
            acc += wS[i + 6] * v6; acc += wS[i + 7] * v7;
        }
        for (; i < m; ++i)
            acc += wS[i] * xcomb[(size_t)sS[i] * 128 + tid];
        __syncthreads();
    }
    h[(size_t)b * 128 + tid] = fmaxf(acc, 0.f);
}

// fused tail: path_in projection + path circuit + epilogue out = M@z + v.
// h is un-normalized (layer-1 gather output); 1/S folds into the raw dot.
__global__ void k_tail(const float* __restrict__ h, const float* __restrict__ piW,
                       const float* __restrict__ pib, const float* __restrict__ RP,
                       const float* __restrict__ M, const float* __restrict__ v,
                       const float* __restrict__ sprev,
                       float* __restrict__ out, int N) {
    __shared__ float pqS[64 * 8];
    __shared__ float zS[64 * 4];
    __shared__ float MS[128];
    __shared__ float vS[32];
    const int tid = threadIdx.x;  // 256
    const int base = blockIdx.x * 64;
    if (tid < 128) MS[tid] = M[tid];
    else if (tid < 160) vS[tid - 128] = v[tid - 128];
    const float invS = __builtin_amdgcn_rcpf(sprev[0]);
    // phase 1: one projection dot per thread
    {
        const int nl = tid >> 2, i = tid & 3;
        const int node = base + nl;
        if (node < N) {
            float raw = 0.f;
            const float4* w4 = (const float4*)(piW + i * 128);
            const float4* h4 = (const float4*)(h + (size_t)node * 128);
#pragma unroll 8
            for (int c4 = 0; c4 < 32; ++c4) {
                float4 w = w4[c4];
                float4 hv = h4[c4];
                raw += w.x * hv.x + w.y * hv.y + w.z * hv.z + w.w * hv.w;
            }
            float dot = pib[i] + invS * raw;
            float halfang = fast_tanh(dot) * (0.5f * PI_HALF);
            float s, c; __sincosf(halfang, &s, &c);
            pqS[nl * 8 + i * 2]     = c;
            pqS[nl * 8 + i * 2 + 1] = s;
        }
    }
    __syncthreads();
    // phase 2: path circuit, one node per lane (lanes 0-63).
    if (tid < 64 && base + tid < N) {
        const float r = 0.70710678118654752f;
        float c0 = pqS[tid * 8 + 0], s0 = pqS[tid * 8 + 1];
        float c1 = pqS[tid * 8 + 2], s1 = pqS[tid * 8 + 3];
        float c2 = pqS[tid * 8 + 4], s2 = pqS[tid * 8 + 5];
        float c3 = pqS[tid * 8 + 6], s3 = pqS[tid * 8 + 7];
        float u0 = r * (c0 - s0), w0 = r * (c0 + s0);
        float u1 = r * (c1 - s1), w1 = r * (c1 + s1);
        float u2 = r * (c2 - s2), w2 = r * (c2 + s2);
        float u3 = r * (c3 - s3), w3 = r * (c3 + s3);
        float sr[16], si[16];
        prod_init(sr, u0, w0, u1, w1, u2, w2, u3, w3);
        rot_first<8>(sr, si, RP);
        rot_pre<4>(sr, si, RP + 8);
        rot_pre<2>(sr, si, RP + 16);
        rot_pre<1>(sr, si, RP + 24);
        cnot_g<8, 4>(sr, si); cnot_g<4, 2>(sr, si); cnot_g<2, 1>(sr, si);
#pragma unroll
        for (int l = 1; l < 3; ++l) {
            const float* P = RP + l * 32;
            rot_pre<8>(sr, si, P);
            rot_pre<4>(sr, si, P + 8);
            rot_pre<2>(sr, si, P + 16);
            rot_pre<1>(sr, si, P + 24);
            cnot_g<8, 4>(sr, si); cnot_g<4, 2>(sr, si); cnot_g<2, 1>(sr, si);
        }
        float z[4]; zexp_g(sr, si, z);
        zS[tid * 4 + 0] = z[0]; zS[tid * 4 + 1] = z[1];
        zS[tid * 4 + 2] = z[2]; zS[tid * 4 + 3] = z[3];
    }
    __syncthreads();
    // phase 3: epilogue, 64 nodes x 32 outputs, coalesced
#pragma unroll
    for (int k = 0; k < 8; ++k) {
        int flat = k * 256 + tid;
        int nl = flat >> 5;
        int o = flat & 31;
        int node = base + nl;
        if (node < N) {
            out[(size_t)node * 32 + o] = vS[o]
                + MS[o * 4 + 0] * zS[nl * 4 + 0] + MS[o * 4 + 1] * zS[nl * 4 + 1]
                + MS[o * 4 + 2] * zS[nl * 4 + 2] + MS[o * 4 + 3] * zS[nl * 4 + 3];
        }
    }
}

// ---------------- launch ----------------------------------------------------

extern "C" void kernel_launch(void* const* d_in, const int* in_sizes, int n_in,
                              void* d_out, int out_size, void* d_ws, size_t ws_size,
                              hipStream_t stream) {
    const float* x     = (const float*)d_in[0];
    const float* W_in  = (const float*)d_in[1];
    const float* b_in  = (const float*)d_in[2];
    const float* linW  = (const float*)d_in[3];
    const float* linb  = (const float*)d_in[4];
    const float* qpW   = (const float*)d_in[5];
    const float* qpb   = (const float*)d_in[6];
    const float* entp  = (const float*)d_in[7];
    const float* aqW   = (const float*)d_in[8];
    const float* aqb   = (const float*)d_in[9];
    const float* akW   = (const float*)d_in[10];
    const float* akb   = (const float*)d_in[11];
    const float* attqp = (const float*)d_in[12];
    const float* pparm = (const float*)d_in[13];
    const float* piW   = (const float*)d_in[14];
    const float* pib   = (const float*)d_in[15];
    const float* poW   = (const float*)d_in[16];
    const float* pob   = (const float*)d_in[17];
    const float* outW  = (const float*)d_in[18];
    const float* outb  = (const float*)d_in[19];
    const int*   ei    = (const int*)d_in[20];

    const int N  = in_sizes[0] / 64;   // 20000
    const int E  = in_sizes[20] / 2;   // 300000
    const int EP = E + N;              // self-loops appended

    float* ws     = (float*)d_ws;
    float* h      = ws;
    float* xcomb  = h      + (size_t)N * 128;
    float* qbuf   = xcomb  + (size_t)N * 128;
    float* kbuf   = qbuf   + (size_t)N * 8;
    float* escore = kbuf   + (size_t)N * 8;
    float* rotbuf = escore + EP;
    float* Mm     = rotbuf + 36 * 8;
    float* vv     = Mm + 128;
    int*   cnt    = (int*)(vv + 32);
    float* sumexp = (float*)(cnt + N);   // 4 slots
    int*   off    = (int*)(sumexp + 4);
    int*   cur    = off + N;
    int*   srcs   = cur + N;
    int*   inv    = srcs + EP;

    const float* rotE = rotbuf;          // 16 matrices
    const float* rotA = rotbuf + 128;    // 8 matrices
    const float* rotP = rotbuf + 192;    // 12 matrices

    const int nb16 = (N + 15) / 16;
    const int nb32 = (N + 31) / 32;
    const int ebl  = (EP + 255) / 256;
    const int eblf = (EP + 127) / 128;

    // 1: zero(cnt,sumexp) + setup + input GEMM
    k_fsi<<<nb32 + 1, 256, 0, stream>>>(entp, attqp, pparm, outW, outb, poW, pob,
                                        rotbuf, Mm, vv, x, W_in, b_in, h,
                                        cnt, sumexp, N);
    // 2: histogram of dsts
    k_hist<<<ebl, 256, 0, stream>>>(ei, cnt, E, EP);
    // 3: exclusive scan
    k_scan<<<1, 1024, 0, stream>>>(cnt, off, cur, N);

    for (int l = 0; l < 2; ++l) {
        const int fillb = (l == 0) ? eblf : 0;
        // 4/7: fill (layer 0 only) + entangle + linear + q/k
        k_entlin<<<fillb + nb16, 128, 0, stream>>>(h, rotE + l * 64,
            linW + (size_t)l * 128 * 128, linb + l * 128,
            qpW + (size_t)l * 128 * 4, qpb + l * 128,
            aqW + (size_t)l * 4 * 128, aqb + l * 4,
            akW + (size_t)l * 4 * 128, akb + l * 4,
            xcomb, qbuf, kbuf, N,
            (l == 0) ? (const float*)nullptr : (const float*)(sumexp + 0),
            fillb, ei, cur, srcs, inv, E, EP);
        // 5/8: dense per-edge attention circuits
        k_att<<<ebl, 256, 0, stream>>>(qbuf, kbuf, ei, rotA + l * 32, inv,
                                       escore, sumexp + l, E, EP);
        // 6/9: per-dst gather (un-normalized, ILP-8)
        k_gather<<<N, 128, 0, stream>>>(xcomb, srcs, escore, off, cnt, h);
    }

    // 10: tail with 1/S fold
    k_tail<<<(N + 63) / 64, 256, 0, stream>>>(h, piW, pib, rotP, Mm, vv,
                                              sumexp + 1, (float*)d_out, N);
}

// Round 9
// 361.829 us; speedup vs baseline: 8.2905x; 1.0197x over previous
//
#include <hip/hip_runtime.h>
#include <math.h>

#define PI_HALF 1.57079632679489662f

__device__ __forceinline__ float fast_tanh(float x) {
    float e = __expf(2.f * x);
    return 1.f - 2.f * __builtin_amdgcn_rcpf(e + 1.f);
}

// ---------------- 4-qubit state helpers (compile-time masks -> registers) ----
// wire w (0..3) maps to amplitude-index bit (3-w), i.e. mask = 8 >> w.

__device__ __forceinline__ void prod_init(float sr[16],
        float c0, float s0, float c1, float s1,
        float c2, float s2, float c3, float s3) {
    float p2[4];
    p2[0] = c0 * c1; p2[1] = c0 * s1; p2[2] = s0 * c1; p2[3] = s0 * s1;
    float p3[8];
#pragma unroll
    for (int j = 0; j < 4; ++j) { p3[2 * j] = p2[j] * c2; p3[2 * j + 1] = p2[j] * s2; }
#pragma unroll
    for (int j = 0; j < 8; ++j) { sr[2 * j] = p3[j] * c3; sr[2 * j + 1] = p3[j] * s3; }
}

template<int M>
__device__ __forceinline__ void had_r(float sr[16]) {
    const float r = 0.70710678118654752f;
#pragma unroll
    for (int i = 0; i < 16; ++i) {
        if (i & M) continue;
        const int j = i | M;
        float ar = sr[i], br = sr[j];
        sr[i] = (ar + br) * r;
        sr[j] = (ar - br) * r;
    }
}

template<int MC, int MT>
__device__ __forceinline__ void cry_r(float sr[16], float c, float s) {
#pragma unroll
    for (int i = 0; i < 16; ++i) {
        if (!(i & MC) || (i & MT)) continue;
        const int j = i | MT;
        float ar = sr[i], br = sr[j];
        sr[i] = c * ar - s * br;
        sr[j] = s * ar + c * br;
    }
}

template<int MC, int MT>
__device__ __forceinline__ void cnot_r(float sr[16]) {
#pragma unroll
    for (int i = 0; i < 16; ++i) {
        if (!(i & MC) || (i & MT)) continue;
        const int j = i | MT;
        float t = sr[i]; sr[i] = sr[j]; sr[j] = t;
    }
}

template<int MC, int MT>
__device__ __forceinline__ void cnot_g(float sr[16], float si[16]) {
#pragma unroll
    for (int i = 0; i < 16; ++i) {
        if (!(i & MC) || (i & MT)) continue;
        const int j = i | MT;
        float tr = sr[i], ti = si[i];
        sr[i] = sr[j]; si[i] = si[j];
        sr[j] = tr;    si[j] = ti;
    }
}

template<int M>
__device__ __forceinline__ void rot_pre(float sr[16], float si[16], const float* __restrict__ u) {
    const float u00r = u[0], u00i = u[1], u01r = u[2], u01i = u[3];
    const float u10r = u[4], u10i = u[5], u11r = u[6], u11i = u[7];
#pragma unroll
    for (int i = 0; i < 16; ++i) {
        if (i & M) continue;
        const int j = i | M;
        float ar = sr[i], ai = si[i], br = sr[j], bi = si[j];
        sr[i] = u00r * ar - u00i * ai + u01r * br - u01i * bi;
        si[i] = u00r * ai + u00i * ar + u01r * bi + u01i * br;
        sr[j] = u10r * ar - u10i * ai + u11r * br - u11i * bi;
        si[j] = u10r * ai + u10i * ar + u11r * bi + u11i * br;
    }
}

// first Rot applied to a purely-real state (si implicitly 0); bitwise-identical
// to rot_pre with ai=bi=0 (dropped terms are exact zeros).
template<int M>
__device__ __forceinline__ void rot_first(float sr[16], float si[16], const float* __restrict__ u) {
    const float u00r = u[0], u00i = u[1], u01r = u[2], u01i = u[3];
    const float u10r = u[4], u10i = u[5], u11r = u[6], u11i = u[7];
#pragma unroll
    for (int i = 0; i < 16; ++i) {
        if (i & M) continue;
        const int j = i | M;
        float ar = sr[i], br = sr[j];
        sr[i] = u00r * ar + u01r * br;
        si[i] = u00i * ar + u01i * br;
        sr[j] = u10r * ar + u11r * br;
        si[j] = u10i * ar + u11i * br;
    }
}

__device__ __forceinline__ void zexp_g(const float sr[16], const float si[16], float z[4]) {
    float p[16];
#pragma unroll
    for (int i = 0; i < 16; ++i) p[i] = sr[i] * sr[i] + si[i] * si[i];
    z[0] = z[1] = z[2] = z[3] = 0.f;
#pragma unroll
    for (int i = 0; i < 16; ++i) {
        z[0] += (i & 8) ? -p[i] : p[i];
        z[1] += (i & 4) ? -p[i] : p[i];
        z[2] += (i & 2) ? -p[i] : p[i];
        z[3] += (i & 1) ? -p[i] : p[i];
    }
}

// ---------------- kernels ---------------------------------------------------

// k_fsi: zero cnt/sumexp + setup (block 0) + input GEMM (blocks 1..).
__global__ void k_fsi(const float* __restrict__ entp, const float* __restrict__ attqp,
                      const float* __restrict__ pparm,
                      const float* __restrict__ outW, const float* __restrict__ outb,
                      const float* __restrict__ poW, const float* __restrict__ pob,
                      float* __restrict__ rotbuf, float* __restrict__ M,
                      float* __restrict__ v,
                      const float* __restrict__ x, const float* __restrict__ W,
                      const float* __restrict__ b, float* __restrict__ h,
                      int* __restrict__ cnt, float* __restrict__ sumexp, int N) {
    __shared__ float xs[32 * 64];
    const int bb = blockIdx.x;
    const int tid = threadIdx.x;  // 256
    {
        const int gid = bb * 256 + tid;
        const int T = gridDim.x * 256;
        for (int i = gid; i < N; i += T) cnt[i] = 0;
        if (gid < 4) sumexp[gid] = 0.f;
    }
    if (bb == 0) {
        const int t = tid;
        if (t < 36) {
            const float* p;
            if (t < 16)      p = entp  + t * 3;
            else if (t < 24) p = attqp + (t - 16) * 3;
            else             p = pparm + (t - 24) * 3;
            float phi = p[0], theta = p[1], omega = p[2];
            float st, ct; sincosf(0.5f * theta, &st, &ct);
            float sp, cp; sincosf(0.5f * (phi + omega), &sp, &cp);
            float sm, cm; sincosf(0.5f * (phi - omega), &sm, &cm);
            float* u = rotbuf + t * 8;
            u[0] =  ct * cp;  u[1] = -ct * sp;
            u[2] = -st * cm;  u[3] = -st * sm;
            u[4] =  st * cm;  u[5] = -st * sm;
            u[6] =  ct * cp;  u[7] =  ct * sp;
        } else if (t >= 64 && t < 192) {
            int t2 = t - 64;
            int o = t2 >> 2, i = t2 & 3;
            float acc = 0.f;
            for (int j = 0; j < 128; ++j) acc += outW[o * 128 + j] * poW[j * 4 + i];
            M[t2] = acc;
        } else if (t >= 192 && t < 224) {
            int o = t - 192;
            float acc = outb[o];
            for (int j = 0; j < 128; ++j) acc += outW[o * 128 + j] * pob[j];
            v[o] = acc;
        }
        return;
    }
    const int base = (bb - 1) * 32;
    for (int idx = tid; idx < 32 * 64; idx += 256) {
        int n = base + (idx >> 6);
        xs[idx] = (n < N) ? x[(size_t)n * 64 + (idx & 63)] : 0.f;
    }
    __syncthreads();
    const int lane = tid & 63;
    const int wv = tid >> 6;
    const int ch0 = lane, ch1 = lane + 64;
    float acc0[8], acc1[8];
#pragma unroll
    for (int n = 0; n < 8; ++n) { acc0[n] = 0.f; acc1[n] = 0.f; }
    const float4* w04 = (const float4*)(W + ch0 * 64);
    const float4* w14 = (const float4*)(W + ch1 * 64);
    for (int c4 = 0; c4 < 16; ++c4) {
        float4 wa = w04[c4];
        float4 wb = w14[c4];
#pragma unroll
        for (int n = 0; n < 8; ++n) {
            float4 hv = *(const float4*)&xs[(wv * 8 + n) * 64 + c4 * 4];
            acc0[n] += wa.x * hv.x + wa.y * hv.y + wa.z * hv.z + wa.w * hv.w;
            acc1[n] += wb.x * hv.x + wb.y * hv.y + wb.z * hv.z + wb.w * hv.w;
        }
    }
    const float b0 = b[ch0];
    const float b1 = b[ch1];
#pragma unroll
    for (int n = 0; n < 8; ++n) {
        int node = base + wv * 8 + n;
        if (node < N) {
            h[(size_t)node * 128 + ch0] = fmaxf(acc0[n] + b0, 0.f);
            h[(size_t)node * 128 + ch1] = fmaxf(acc1[n] + b1, 0.f);
        }
    }
}

__global__ void k_hist(const int* __restrict__ ei, int* __restrict__ cnt, int E, int EP) {
    int e = blockIdx.x * blockDim.x + threadIdx.x;
    if (e >= EP) return;
    int d_ = (e < E) ? ei[E + e] : e - E;
    atomicAdd(&cnt[d_], 1);
}

__global__ void k_scan(const int* __restrict__ cnt, int* __restrict__ off,
                       int* __restrict__ cur, int N) {
    __shared__ int tot[1024];
    const int t = threadIdx.x;
    const int chunk = (N + 1023) >> 10;
    const int s0 = t * chunk;
    const int s1 = min(s0 + chunk, N);
    int sum = 0;
    for (int i = s0; i < s1; ++i) sum += cnt[i];
    tot[t] = sum;
    __syncthreads();
    for (int d = 1; d < 1024; d <<= 1) {
        int v = (t >= d) ? tot[t - d] : 0;
        __syncthreads();
        tot[t] += v;
        __syncthreads();
    }
    int run = (t == 0) ? 0 : tot[t - 1];
    for (int i = s0; i < s1; ++i) {
        off[i] = run; cur[i] = run;
        run += cnt[i];
    }
}

// k_qke: barrier-free, LDS-free role-split kernel.
// Blocks [0, fillb): counting-sort fill (layer 0 only).
// Blocks [fillb, fillb+dotb): q/k dots, one (node, which) pair per thread.
// Blocks [fillb+dotb, ...): entangle circuit, one node per thread (full lanes).
// h scale (1/S_prev) applied per element before use (matches staged-scale order).
__global__ void k_qke(const float* __restrict__ h,
                      const float* __restrict__ aqW, const float* __restrict__ aqb,
                      const float* __restrict__ akW, const float* __restrict__ akb,
                      const float* __restrict__ rotE2,
                      float* __restrict__ qbuf, float* __restrict__ kbuf,
                      float* __restrict__ xq, int N,
                      const float* __restrict__ sprev,
                      int fillb, int dotb, const int* __restrict__ ei,
                      int* __restrict__ cur, int* __restrict__ srcs,
                      int* __restrict__ inv, int E, int EP) {
    int bb = blockIdx.x;
    const int tid = threadIdx.x;  // 256
    if (bb < fillb) {
        int e = bb * 256 + tid;
        if (e < EP) {
            int s_, d_;
            if (e < E) { s_ = ei[e]; d_ = ei[E + e]; } else { s_ = d_ = e - E; }
            int pos = atomicAdd(&cur[d_], 1);
            srcs[pos] = s_;
            inv[e] = pos;
        }
        return;
    }
    bb -= fillb;
    const float scale = sprev ? __builtin_amdgcn_rcpf(sprev[0]) : 1.0f;
    if (bb < dotb) {
        // ---- dot role: t = node*8 + which; 8 threads share one h row ----
        const int t = bb * 256 + tid;
        const int node = t >> 3;
        if (node >= N) return;
        const int which = t & 7;
        const int qi = which & 3;
        const float4* h4 = (const float4*)(h + (size_t)node * 128);
        const float4* w4 = (const float4*)(((which < 4) ? aqW : akW) + qi * 128);
        float dot = (which < 4) ? aqb[qi] : akb[qi];
        for (int c4 = 0; c4 < 32; ++c4) {
            float4 hv = h4[c4];
            hv.x *= scale; hv.y *= scale; hv.z *= scale; hv.w *= scale;
            float4 w = w4[c4];
            dot += w.x * hv.x + w.y * hv.y + w.z * hv.z + w.w * hv.w;
        }
        float halfang = fast_tanh(dot) * (0.5f * PI_HALF);
        float s, c; __sincosf(halfang, &s, &c);
        float* dst = ((which < 4) ? qbuf : kbuf) + (size_t)node * 8 + qi * 2;
        dst[0] = c; dst[1] = s;
        return;
    }
    bb -= dotb;
    // ---- circuit role: one node per thread, all 64 lanes active ----
    const int node = bb * 256 + tid;
    if (node >= N) return;
    float4 hv = *(const float4*)(h + (size_t)node * 128);
    hv.x *= scale; hv.y *= scale; hv.z *= scale; hv.w *= scale;
    float c0, s0, c1, s1, c2, s2, c3, s3;
    { float a = fast_tanh(hv.x) * (0.5f * PI_HALF); __sincosf(a, &s0, &c0); }
    { float a = fast_tanh(hv.y) * (0.5f * PI_HALF); __sincosf(a, &s1, &c1); }
    { float a = fast_tanh(hv.z) * (0.5f * PI_HALF); __sincosf(a, &s2, &c2); }
    { float a = fast_tanh(hv.w) * (0.5f * PI_HALF); __sincosf(a, &s3, &c3); }
    float sr[16], si[16];
    prod_init(sr, c0, s0, c1, s1, c2, s2, c3, s3);
    cnot_r<8, 4>(sr); cnot_r<4, 2>(sr); cnot_r<2, 1>(sr);
    rot_first<8>(sr, si, rotE2);
    rot_pre<4>(sr, si, rotE2 + 8);
    rot_pre<2>(sr, si, rotE2 + 16);
    rot_pre<1>(sr, si, rotE2 + 24);
    cnot_g<8, 1>(sr, si);
    cnot_g<8, 4>(sr, si); cnot_g<4, 2>(sr, si); cnot_g<2, 1>(sr, si);
    const float* P = rotE2 + 32;
    rot_pre<8>(sr, si, P);
    rot_pre<4>(sr, si, P + 8);
    rot_pre<2>(sr, si, P + 16);
    rot_pre<1>(sr, si, P + 24);
    cnot_g<8, 1>(sr, si);
    float z[4]; zexp_g(sr, si, z);
    *(float4*)&xq[(size_t)node * 4] = make_float4(z[0], z[1], z[2], z[3]);
}

// k_linatt: role-split. Blocks [0, nb16): xcomb GEMM (16-node tile; stage
// scaled h; 2ch x 8n blocking; xq from global). Blocks [nb16, ..): per-edge
// attention circuits (full lane occupancy) -> escore (slot-ordered) + sumexp.
#define HS_STRIDE 132
__global__ void k_linatt(const float* __restrict__ h, const float* __restrict__ xq,
                         const float* __restrict__ linW, const float* __restrict__ linb,
                         const float* __restrict__ qpW, const float* __restrict__ qpb,
                         float* __restrict__ xcomb, int N,
                         const float* __restrict__ sprev, int nb16,
                         const float* __restrict__ qb, const float* __restrict__ kb,
                         const int* __restrict__ ei, const float* __restrict__ RA,
                         const int* __restrict__ inv, float* __restrict__ escore,
                         float* __restrict__ sumexp, int E, int EP) {
    __shared__ float hs[16 * HS_STRIDE];
    __shared__ float red[2];
    const int tid = threadIdx.x;  // 128
    if (blockIdx.x >= nb16) {
        // -------- att role --------
        int e = (blockIdx.x - nb16) * 128 + tid;
        float ex = 0.f;
        if (e < EP) {
            int s_, d_;
            if (e < E) { s_ = ei[e]; d_ = ei[E + e]; } else { s_ = d_ = e - E; }
            float4 qa = *(const float4*)&qb[(size_t)s_ * 8];
            float4 qc = *(const float4*)&qb[(size_t)s_ * 8 + 4];
            float4 ka = *(const float4*)&kb[(size_t)d_ * 8];
            float4 kc = *(const float4*)&kb[(size_t)d_ * 8 + 4];
            float sr[16], si[16];
            prod_init(sr, qa.x, qa.y, qa.z, qa.w, qc.x, qc.y, qc.z, qc.w);
            had_r<8>(sr); had_r<4>(sr); had_r<2>(sr); had_r<1>(sr);
            cry_r<8, 4>(sr, ka.x, ka.y);
            cry_r<4, 2>(sr, ka.z, ka.w);
            cry_r<2, 1>(sr, kc.x, kc.y);
            cry_r<1, 8>(sr, kc.z, kc.w);
            rot_first<8>(sr, si, RA);
            rot_pre<4>(sr, si, RA + 8);
            rot_pre<2>(sr, si, RA + 16);
            rot_pre<1>(sr, si, RA + 24);
            float p0  = sr[0]  * sr[0]  + si[0]  * si[0];
            float p1  = sr[1]  * sr[1]  + si[1]  * si[1];
            float p2  = sr[2]  * sr[2]  + si[2]  * si[2];
            float p4  = sr[4]  * sr[4]  + si[4]  * si[4];
            float p8  = sr[8]  * sr[8]  + si[8]  * si[8];
            float p7  = sr[7]  * sr[7]  + si[7]  * si[7];
            float p11 = sr[11] * sr[11] + si[11] * si[11];
            float p13 = sr[13] * sr[13] + si[13] * si[13];
            float p14 = sr[14] * sr[14] + si[14] * si[14];
            float p15 = sr[15] * sr[15] + si[15] * si[15];
            float sc = (p0 - p15) + 0.5f * ((p1 + p2 + p4 + p8) - (p7 + p11 + p13 + p14));
            ex = __expf(sc);
            escore[inv[e]] = ex;
        }
        float wsum = ex;
#pragma unroll
        for (int d = 32; d; d >>= 1) wsum += __shfl_xor(wsum, d, 64);
        if ((tid & 63) == 0) red[tid >> 6] = wsum;
        __syncthreads();
        if (tid == 0) atomicAdd(sumexp, red[0] + red[1]);
        return;
    }
    // -------- GEMM role --------
    const int base = blockIdx.x * 16;
    const float scale = sprev ? __builtin_amdgcn_rcpf(sprev[0]) : 1.0f;
    for (int idx = tid; idx < 16 * 32; idx += 128) {
        int n = idx >> 5, c4 = idx & 31;
        int node = base + n;
        float4 hv = (node < N) ? *(const float4*)&h[(size_t)node * 128 + c4 * 4]
                               : make_float4(0.f, 0.f, 0.f, 0.f);
        hv.x *= scale; hv.y *= scale; hv.z *= scale; hv.w *= scale;
        *(float4*)&hs[n * HS_STRIDE + c4 * 4] = hv;
    }
    __syncthreads();
    const int lane = tid & 63;
    const int nh = tid >> 6;
    const int ch0 = lane, ch1 = lane + 64;
    float acc0[8], acc1[8];
#pragma unroll
    for (int n = 0; n < 8; ++n) { acc0[n] = 0.f; acc1[n] = 0.f; }
    const float4* w04 = (const float4*)(linW + ch0 * 128);
    const float4* w14 = (const float4*)(linW + ch1 * 128);
    for (int c4 = 0; c4 < 32; ++c4) {
        float4 wa = w04[c4];
        float4 wb = w14[c4];
#pragma unroll
        for (int n = 0; n < 8; ++n) {
            float4 hv = *(const float4*)&hs[(nh * 8 + n) * HS_STRIDE + c4 * 4];
            acc0[n] += wa.x * hv.x + wa.y * hv.y + wa.z * hv.z + wa.w * hv.w;
            acc1[n] += wb.x * hv.x + wb.y * hv.y + wb.z * hv.z + wb.w * hv.w;
        }
    }
    const float b0 = linb[ch0] + qpb[ch0];
    const float b1 = linb[ch1] + qpb[ch1];
    const float q00 = qpW[ch0 * 4 + 0], q01 = qpW[ch0 * 4 + 1];
    const float q02 = qpW[ch0 * 4 + 2], q03 = qpW[ch0 * 4 + 3];
    const float q10 = qpW[ch1 * 4 + 0], q11 = qpW[ch1 * 4 + 1];
    const float q12 = qpW[ch1 * 4 + 2], q13 = qpW[ch1 * 4 + 3];
#pragma unroll
    for (int n = 0; n < 8; ++n) {
        const int nl = nh * 8 + n;
        const int node = base + nl;
        if (node < N) {
            float4 xv = *(const float4*)&xq[(size_t)node * 4];
            xcomb[(size_t)node * 128 + ch0] = acc0[n] + b0
                + q00 * xv.x + q01 * xv.y + q02 * xv.z + q03 * xv.w;
            xcomb[(size_t)node * 128 + ch1] = acc1[n] + b1
                + q10 * xv.x + q11 * xv.y + q12 * xv.z + q13 * xv.w;
        }
    }
}

// one block per dst: h_raw[d,:] = relu(sum escore*xcomb[src,:]) (un-normalized;
// 1/S applied downstream since relu(x)/S == relu(x/S) for S>0). ILP-8 loads.
__global__ void k_gather(const float* __restrict__ xcomb, const int* __restrict__ srcs,
                         const float* __restrict__ escore, const int* __restrict__ off,
                         const int* __restrict__ cnt, float* __restrict__ h) {
    __shared__ int sS[128];
    __shared__ float wS[128];
    const int b = blockIdx.x;
    const int tid = threadIdx.x;  // 128
    const int start = off[b];
    const int num = cnt[b];
    float acc = 0.f;
    for (int base = 0; base < num; base += 128) {
        int m = min(128, num - base);
        if (tid < m) {
            sS[tid] = srcs[start + base + tid];
            wS[tid] = escore[start + base + tid];
        }
        __syncthreads();
        int i = 0;
        for (; i + 8 <= m; i += 8) {
            float v0 = xcomb[(size_t)sS[i + 0] * 128 + tid];
            float v1 = xcomb[(size_t)sS[i + 1] * 128 + tid];
            float v2 = xcomb[(size_t)sS[i + 2] * 128 + tid];
            float v3 = xcomb[(size_t)sS[i + 3] * 128 + tid];
            float v4 = xcomb[(size_t)sS[i + 4] * 128 + tid];
            float v5 = xcomb[(size_t)sS[i + 5] * 128 + tid];
            float v6 = xcomb[(size_t)sS[i + 6] * 128 + tid];
            float v7 = xcomb[(size_t)sS[i + 7] * 128 + tid];
            acc += wS[i + 0] * v0; acc += wS[i + 1] * v1;
            acc += wS[i + 2] * v2; acc += wS[i + 3] * v3;
            acc += wS[i + 4] * v4; acc += wS[i + 5] * v5;
            acc += wS[i + 6] * v6; acc += wS[i + 7] * v7;
        }
        for (; i < m; ++i)
            acc += wS[i] * xcomb[(size_t)sS[i] * 128 + tid];
        __syncthreads();
    }
    h[(size_t)b * 128 + tid] = fmaxf(acc, 0.f);
}

// fused tail: path_in projection + path circuit + epilogue out = M@z + v.
__global__ void k_tail(const float* __restrict__ h, const float* __restrict__ piW,
                       const float* __restrict__ pib, const float* __restrict__ RP,
                       const float* __restrict__ M, const float* __restrict__ v,
                       const float* __restrict__ sprev,
                       float* __restrict__ out, int N) {
    __shared__ float pqS[64 * 8];
    __shared__ float zS[64 * 4];
    __shared__ float MS[128];
    __shared__ float vS[32];
    const int tid = threadIdx.x;  // 256
    const int base = blockIdx.x * 64;
    if (tid < 128) MS[tid] = M[tid];
    else if (tid < 160) vS[tid - 128] = v[tid - 128];
    const float invS = __builtin_amdgcn_rcpf(sprev[0]);
    {
        const int nl = tid >> 2, i = tid & 3;
        const int node = base + nl;
        if (node < N) {
            float raw = 0.f;
            const float4* w4 = (const float4*)(piW + i * 128);
            const float4* h4 = (const float4*)(h + (size_t)node * 128);
#pragma unroll 8
            for (int c4 = 0; c4 < 32; ++c4) {
                float4 w = w4[c4];
                float4 hv = h4[c4];
                raw += w.x * hv.x + w.y * hv.y + w.z * hv.z + w.w * hv.w;
            }
            float dot = pib[i] + invS * raw;
            float halfang = fast_tanh(dot) * (0.5f * PI_HALF);
            float s, c; __sincosf(halfang, &s, &c);
            pqS[nl * 8 + i * 2]     = c;
            pqS[nl * 8 + i * 2 + 1] = s;
        }
    }
    __syncthreads();
    if (tid < 64 && base + tid < N) {
        const float r = 0.70710678118654752f;
        float c0 = pqS[tid * 8 + 0], s0 = pqS[tid * 8 + 1];
        float c1 = pqS[tid * 8 + 2], s1 = pqS[tid * 8 + 3];
        float c2 = pqS[tid * 8 + 4], s2 = pqS[tid * 8 + 5];
        float c3 = pqS[tid * 8 + 6], s3 = pqS[tid * 8 + 7];
        float u0 = r * (c0 - s0), w0 = r * (c0 + s0);
        float u1 = r * (c1 - s1), w1 = r * (c1 + s1);
        float u2 = r * (c2 - s2), w2 = r * (c2 + s2);
        float u3 = r * (c3 - s3), w3 = r * (c3 + s3);
        float sr[16], si[16];
        prod_init(sr, u0, w0, u1, w1, u2, w2, u3, w3);
        rot_first<8>(sr, si, RP);
        rot_pre<4>(sr, si, RP + 8);
        rot_pre<2>(sr, si, RP + 16);
        rot_pre<1>(sr, si, RP + 24);
        cnot_g<8, 4>(sr, si); cnot_g<4, 2>(sr, si); cnot_g<2, 1>(sr, si);
#pragma unroll
        for (int l = 1; l < 3; ++l) {
            const float* P = RP + l * 32;
            rot_pre<8>(sr, si, P);
            rot_pre<4>(sr, si, P + 8);
            rot_pre<2>(sr, si, P + 16);
            rot_pre<1>(sr, si, P + 24);
            cnot_g<8, 4>(sr, si); cnot_g<4, 2>(sr, si); cnot_g<2, 1>(sr, si);
        }
        float z[4]; zexp_g(sr, si, z);
        zS[tid * 4 + 0] = z[0]; zS[tid * 4 + 1] = z[1];
        zS[tid * 4 + 2] = z[2]; zS[tid * 4 + 3] = z[3];
    }
    __syncthreads();
#pragma unroll
    for (int k = 0; k < 8; ++k) {
        int flat = k * 256 + tid;
        int nl = flat >> 5;
        int o = flat & 31;
        int node = base + nl;
        if (node < N) {
            out[(size_t)node * 32 + o] = vS[o]
                + MS[o * 4 + 0] * zS[nl * 4 + 0] + MS[o * 4 + 1] * zS[nl * 4 + 1]
                + MS[o * 4 + 2] * zS[nl * 4 + 2] + MS[o * 4 + 3] * zS[nl * 4 + 3];
        }
    }
}

// ---------------- launch ----------------------------------------------------

extern "C" void kernel_launch(void* const* d_in, const int* in_sizes, int n_in,
                              void* d_out, int out_size, void* d_ws, size_t ws_size,
                              hipStream_t stream) {
    const float* x     = (const float*)d_in[0];
    const float* W_in  = (const float*)d_in[1];
    const float* b_in  = (const float*)d_in[2];
    const float* linW  = (const float*)d_in[3];
    const float* linb  = (const float*)d_in[4];
    const float* qpW   = (const float*)d_in[5];
    const float* qpb   = (const float*)d_in[6];
    const float* entp  = (const float*)d_in[7];
    const float* aqW   = (const float*)d_in[8];
    const float* aqb   = (const float*)d_in[9];
    const float* akW   = (const float*)d_in[10];
    const float* akb   = (const float*)d_in[11];
    const float* attqp = (const float*)d_in[12];
    const float* pparm = (const float*)d_in[13];
    const float* piW   = (const float*)d_in[14];
    const float* pib   = (const float*)d_in[15];
    const float* poW   = (const float*)d_in[16];
    const float* pob   = (const float*)d_in[17];
    const float* outW  = (const float*)d_in[18];
    const float* outb  = (const float*)d_in[19];
    const int*   ei    = (const int*)d_in[20];

    const int N  = in_sizes[0] / 64;   // 20000
    const int E  = in_sizes[20] / 2;   // 300000
    const int EP = E + N;              // self-loops appended

    float* ws     = (float*)d_ws;
    float* h      = ws;
    float* xcomb  = h      + (size_t)N * 128;
    float* qbuf   = xcomb  + (size_t)N * 128;
    float* kbuf   = qbuf   + (size_t)N * 8;
    float* escore = kbuf   + (size_t)N * 8;
    float* rotbuf = escore + EP;
    float* Mm     = rotbuf + 36 * 8;
    float* vv     = Mm + 128;
    int*   cnt    = (int*)(vv + 32);
    float* sumexp = (float*)(cnt + N);   // 4 slots
    int*   off    = (int*)(sumexp + 4);
    int*   cur    = off + N;
    int*   srcs   = cur + N;
    int*   inv    = srcs + EP;
    float* xq     = (float*)(inv + EP);  // N*4

    const float* rotE = rotbuf;          // 16 matrices
    const float* rotA = rotbuf + 128;    // 8 matrices
    const float* rotP = rotbuf + 192;    // 12 matrices

    const int nb16 = (N + 15) / 16;
    const int nb32 = (N + 31) / 32;
    const int ebl  = (EP + 255) / 256;      // 256-thr edge blocks
    const int ebl128 = (EP + 127) / 128;    // 128-thr edge blocks
    const int dotb = (N * 8 + 255) / 256;   // q/k dot blocks
    const int circb = (N + 255) / 256;      // circuit blocks

    // 1: zero(cnt,sumexp) + setup + input GEMM
    k_fsi<<<nb32 + 1, 256, 0, stream>>>(entp, attqp, pparm, outW, outb, poW, pob,
                                        rotbuf, Mm, vv, x, W_in, b_in, h,
                                        cnt, sumexp, N);
    // 2: histogram of dsts
    k_hist<<<ebl, 256, 0, stream>>>(ei, cnt, E, EP);
    // 3: exclusive scan
    k_scan<<<1, 1024, 0, stream>>>(cnt, off, cur, N);

    for (int l = 0; l < 2; ++l) {
        const int fillb = (l == 0) ? ebl : 0;
        const float* sprev = (l == 0) ? (const float*)nullptr
                                      : (const float*)(sumexp + 0);
        // 4/7: fill (L0) + q/k dots + ent circuits (no barriers, no LDS)
        k_qke<<<fillb + dotb + circb, 256, 0, stream>>>(h,
            aqW + (size_t)l * 4 * 128, aqb + l * 4,
            akW + (size_t)l * 4 * 128, akb + l * 4,
            rotE + l * 64, qbuf, kbuf, xq, N, sprev,
            fillb, dotb, ei, cur, srcs, inv, E, EP);
        // 5/8: xcomb GEMM + per-edge attention (role-split, co-scheduled)
        k_linatt<<<nb16 + ebl128, 128, 0, stream>>>(h, xq,
            linW + (size_t)l * 128 * 128, linb + l * 128,
            qpW + (size_t)l * 128 * 4, qpb + l * 128,
            xcomb, N, sprev, nb16,
            qbuf, kbuf, ei, rotA + l * 32, inv, escore, sumexp + l, E, EP);
        // 6/9: per-dst gather (un-normalized, ILP-8)
        k_gather<<<N, 128, 0, stream>>>(xcomb, srcs, escore, off, cnt, h);
    }

    // 10: tail with 1/S fold
    k_tail<<<(N + 63) / 64, 256, 0, stream>>>(h, piW, pib, rotP, Mm, vv,
                                              sumexp + 1, (float*)d_out, N);
}